// Round 1
// baseline (702.903 us; speedup 1.0000x reference)
//
#include <hip/hip_runtime.h>
#include <stdint.h>

typedef __bf16 bf16x8 __attribute__((ext_vector_type(8)));
typedef float f32x4 __attribute__((ext_vector_type(4)));

__device__ __forceinline__ unsigned short f2bf(float f){
  union { float f; unsigned u; } c; c.f = f;
  unsigned u = c.u;
  unsigned r = u + 0x7FFFu + ((u >> 16) & 1u);
  return (unsigned short)(r >> 16);
}
__device__ __forceinline__ float bf2f(unsigned short h){
  union { unsigned u; float f; } c; c.u = ((unsigned)h) << 16;
  return c.f;
}

// ---------------- CSR build (group edges by dst) ----------------
__global__ void k_hist(const int* __restrict__ ei, int E, int Nn, int* __restrict__ counts){
  int total = E + Nn;
  for (int e = blockIdx.x*blockDim.x + threadIdx.x; e < total; e += gridDim.x*blockDim.x){
    int d = (e < E) ? ei[E + e] : (e - E);
    atomicAdd(&counts[d], 1);
  }
}

__global__ __launch_bounds__(1024) void k_scan(const int* __restrict__ counts, int* __restrict__ rowptr, int n){
  __shared__ int wsum[17];
  __shared__ int carry_s;
  int tid = threadIdx.x, lane = tid & 63, wid = tid >> 6;
  if (tid == 0){ carry_s = 0; rowptr[0] = 0; }
  __syncthreads();
  for (int base = 0; base < n; base += 1024){
    int i = base + tid;
    int v = (i < n) ? counts[i] : 0;
    int iv = v;
    #pragma unroll
    for (int off = 1; off < 64; off <<= 1){
      int t = __shfl_up(iv, off, 64);
      if (lane >= off) iv += t;
    }
    if (lane == 63) wsum[wid] = iv;
    __syncthreads();
    if (tid == 0){
      int run = 0;
      for (int w = 0; w < 16; ++w){ int t = wsum[w]; wsum[w] = run; run += t; }
      wsum[16] = run;
    }
    __syncthreads();
    int outv = iv + wsum[wid] + carry_s;
    if (i < n) rowptr[i + 1] = outv;
    int total = wsum[16];
    __syncthreads();
    if (tid == 0) carry_s += total;
    __syncthreads();
  }
}

__global__ void k_scatter(const int* __restrict__ ei, int E, int Nn, const int* __restrict__ rowptr,
                          int* __restrict__ cursor, int* __restrict__ srcs){
  int total = E + Nn;
  for (int e = blockIdx.x*blockDim.x + threadIdx.x; e < total; e += gridDim.x*blockDim.x){
    int s, d;
    if (e < E){ s = ei[e]; d = ei[E + e]; } else { s = d = e - E; }
    int pos = rowptr[d] + atomicAdd(&cursor[d], 1);
    srcs[pos] = s;
  }
}

// ---------------- conversions ----------------
__global__ void k_f32_to_bf16(const float* __restrict__ in, unsigned short* __restrict__ out, int n4){
  int i = blockIdx.x*blockDim.x + threadIdx.x;
  if (i >= n4) return;
  float4 v = reinterpret_cast<const float4*>(in)[i];
  ushort4 o;
  o.x = f2bf(v.x); o.y = f2bf(v.y); o.z = f2bf(v.z); o.w = f2bf(v.w);
  reinterpret_cast<ushort4*>(out)[i] = o;
}

__global__ void k_transpose_w(const float* __restrict__ W, unsigned short* __restrict__ Wt){
  int t = blockIdx.x*blockDim.x + threadIdx.x; // 65536 threads
  int k = t >> 8, c = t & 255;
  Wt[c*256 + k] = f2bf(W[k*256 + c]);
}

// ---------------- GEMM: [M,256] x [256,256] -> [M,256], bf16 in/out ----------------
// one wave computes a 16x16 tile; 16 waves per block cover all 256 cols of 16 rows.
__global__ __launch_bounds__(1024) void k_gemm(const unsigned short* __restrict__ A,
                                               const unsigned short* __restrict__ Wt,
                                               unsigned short* __restrict__ H){
  int rt = blockIdx.x;
  int wid = threadIdx.x >> 6;     // col tile 0..15
  int lane = threadIdx.x & 63;
  int r = lane & 15, kg = lane >> 4;
  const unsigned short* arow = A  + (size_t)(rt*16  + r)*256 + kg*8;
  const unsigned short* brow = Wt + (size_t)(wid*16 + r)*256 + kg*8;
  f32x4 acc = {0.f,0.f,0.f,0.f};
  #pragma unroll
  for (int k0 = 0; k0 < 256; k0 += 32){
    bf16x8 a = *reinterpret_cast<const bf16x8*>(arow + k0);
    bf16x8 b = *reinterpret_cast<const bf16x8*>(brow + k0);
    acc = __builtin_amdgcn_mfma_f32_16x16x32_bf16(a, b, acc, 0, 0, 0);
  }
  int col  = wid*16 + r;
  int row0 = rt*16 + kg*4;
  #pragma unroll
  for (int i = 0; i < 4; ++i)
    H[(size_t)(row0 + i)*256 + col] = f2bf(acc[i]);
}

// ---------------- attention logits per node: als/ald [N,4] ----------------
__global__ void k_al(const unsigned short* __restrict__ H, const float* __restrict__ asrc,
                     const float* __restrict__ adst, float* __restrict__ als,
                     float* __restrict__ ald, int Nn){
  int gid = blockIdx.x*blockDim.x + threadIdx.x;
  int node = gid >> 6, lane = gid & 63;
  if (node >= Nn) return;
  ushort4 hv = *reinterpret_cast<const ushort4*>(H + (size_t)node*256 + lane*4);
  float4 as = *reinterpret_cast<const float4*>(asrc + lane*4);
  float4 ad = *reinterpret_cast<const float4*>(adst + lane*4);
  float h0 = bf2f(hv.x), h1 = bf2f(hv.y), h2 = bf2f(hv.z), h3 = bf2f(hv.w);
  float ps = h0*as.x + h1*as.y + h2*as.z + h3*as.w;
  float pd = h0*ad.x + h1*ad.y + h2*ad.z + h3*ad.w;
  #pragma unroll
  for (int off = 1; off < 16; off <<= 1){
    ps += __shfl_xor(ps, off, 64);
    pd += __shfl_xor(pd, off, 64);
  }
  if ((lane & 15) == 0){
    als[node*4 + (lane>>4)] = ps;
    ald[node*4 + (lane>>4)] = pd;
  }
}

// ---------------- aggregation: one wave per destination node ----------------
// MODE 0: concat heads, +bias, ELU, write bf16 activation [N,256]
// MODE 1: mean heads, +bias, log_softmax over 64 classes, write f32 [N,64]
template<int MODE>
__global__ void k_agg(const unsigned short* __restrict__ Hm, const int* __restrict__ rowptr,
                      const int* __restrict__ srcs, const float* __restrict__ als,
                      const float* __restrict__ ald, const float* __restrict__ bias,
                      unsigned short* __restrict__ actout, float* __restrict__ finalout, int Nn){
  int gid = blockIdx.x*blockDim.x + threadIdx.x;
  int node = gid >> 6, lane = gid & 63;
  if (node >= Nn) return;
  int hd = lane >> 4;
  int beg = rowptr[node], end = rowptr[node + 1];
  int deg = end - beg;
  float4 aldv = *reinterpret_cast<const float4*>(ald + node*4);
  float ald0 = aldv.x, ald1 = aldv.y, ald2 = aldv.z, ald3 = aldv.w;
  float aldh = (hd == 0) ? ald0 : (hd == 1) ? ald1 : (hd == 2) ? ald2 : ald3;

  // pass 1: per-head max of leaky_relu(als[src]+ald[node]) over edges
  float m0 = -1e30f, m1 = -1e30f, m2 = -1e30f, m3 = -1e30f;
  for (int jb = 0; jb < deg; jb += 64){
    int j = jb + lane;
    if (j < deg){
      int sj = srcs[beg + j];
      float4 a = *reinterpret_cast<const float4*>(als + sj*4);
      float l0 = a.x + ald0; l0 = l0 > 0.f ? l0 : 0.2f*l0; m0 = fmaxf(m0, l0);
      float l1 = a.y + ald1; l1 = l1 > 0.f ? l1 : 0.2f*l1; m1 = fmaxf(m1, l1);
      float l2 = a.z + ald2; l2 = l2 > 0.f ? l2 : 0.2f*l2; m2 = fmaxf(m2, l2);
      float l3 = a.w + ald3; l3 = l3 > 0.f ? l3 : 0.2f*l3; m3 = fmaxf(m3, l3);
    }
  }
  #pragma unroll
  for (int off = 1; off < 64; off <<= 1){
    m0 = fmaxf(m0, __shfl_xor(m0, off, 64));
    m1 = fmaxf(m1, __shfl_xor(m1, off, 64));
    m2 = fmaxf(m2, __shfl_xor(m2, off, 64));
    m3 = fmaxf(m3, __shfl_xor(m3, off, 64));
  }
  float mh = (hd == 0) ? m0 : (hd == 1) ? m1 : (hd == 2) ? m2 : m3;

  // pass 2: accumulate w*h and denominator (unnormalized)
  float s = 0.f, acc0 = 0.f, acc1 = 0.f, acc2 = 0.f, acc3 = 0.f;
  for (int cb = 0; cb < deg; cb += 64){
    int chunk = min(64, deg - cb);
    int mysrc = 0;
    if (cb + lane < deg) mysrc = srcs[beg + cb + lane];
    for (int j = 0; j < chunk; ++j){
      int sj = __shfl(mysrc, j, 64);
      float l = als[sj*4 + hd] + aldh; l = l > 0.f ? l : 0.2f*l;
      float w = __expf(l - mh);
      s += w;
      ushort4 hv = *reinterpret_cast<const ushort4*>(Hm + (size_t)sj*256 + lane*4);
      acc0 += w*bf2f(hv.x); acc1 += w*bf2f(hv.y);
      acc2 += w*bf2f(hv.z); acc3 += w*bf2f(hv.w);
    }
  }
  float inv = 1.f / s;

  if (MODE == 0){
    float4 bv = *reinterpret_cast<const float4*>(bias + lane*4);
    float o0 = acc0*inv + bv.x, o1 = acc1*inv + bv.y, o2 = acc2*inv + bv.z, o3 = acc3*inv + bv.w;
    o0 = o0 > 0.f ? o0 : __expf(o0) - 1.f;
    o1 = o1 > 0.f ? o1 : __expf(o1) - 1.f;
    o2 = o2 > 0.f ? o2 : __expf(o2) - 1.f;
    o3 = o3 > 0.f ? o3 : __expf(o3) - 1.f;
    ushort4 o; o.x = f2bf(o0); o.y = f2bf(o1); o.z = f2bf(o2); o.w = f2bf(o3);
    *reinterpret_cast<ushort4*>(actout + (size_t)node*256 + lane*4) = o;
  } else {
    // mean over heads: lanes L, L^16, L^32, L^48 hold same d, different head
    float v0 = acc0*inv, v1 = acc1*inv, v2 = acc2*inv, v3 = acc3*inv;
    #pragma unroll
    for (int off = 16; off < 64; off <<= 1){
      v0 += __shfl_xor(v0, off, 64);
      v1 += __shfl_xor(v1, off, 64);
      v2 += __shfl_xor(v2, off, 64);
      v3 += __shfl_xor(v3, off, 64);
    }
    int d0 = (lane & 15)*4;
    float4 bv = *reinterpret_cast<const float4*>(bias + d0);
    v0 = v0*0.25f + bv.x; v1 = v1*0.25f + bv.y; v2 = v2*0.25f + bv.z; v3 = v3*0.25f + bv.w;
    // log_softmax over 64 classes held by the 16-lane group
    float mx = fmaxf(fmaxf(v0, v1), fmaxf(v2, v3));
    #pragma unroll
    for (int off = 1; off < 16; off <<= 1) mx = fmaxf(mx, __shfl_xor(mx, off, 64));
    float se = __expf(v0 - mx) + __expf(v1 - mx) + __expf(v2 - mx) + __expf(v3 - mx);
    #pragma unroll
    for (int off = 1; off < 16; off <<= 1) se += __shfl_xor(se, off, 64);
    float lse = mx + __logf(se);
    if (lane < 16){
      float4 o; o.x = v0 - lse; o.y = v1 - lse; o.z = v2 - lse; o.w = v3 - lse;
      *reinterpret_cast<float4*>(finalout + (size_t)node*64 + d0) = o;
    }
  }
}

extern "C" void kernel_launch(void* const* d_in, const int* in_sizes, int n_in,
                              void* d_out, int out_size, void* d_ws, size_t ws_size,
                              hipStream_t stream){
  const float* x     = (const float*)d_in[0];
  const int*   ei    = (const int*)  d_in[1];
  const float* W1    = (const float*)d_in[2];
  const float* asrc1 = (const float*)d_in[3];
  const float* adst1 = (const float*)d_in[4];
  const float* b1    = (const float*)d_in[5];
  const float* W2    = (const float*)d_in[6];
  const float* asrc2 = (const float*)d_in[7];
  const float* adst2 = (const float*)d_in[8];
  const float* b2    = (const float*)d_in[9];
  const float* W3    = (const float*)d_in[10];
  const float* asrc3 = (const float*)d_in[11];
  const float* adst3 = (const float*)d_in[12];
  const float* b3    = (const float*)d_in[13];
  float* out = (float*)d_out;

  int N = in_sizes[0] / 256;
  int E = in_sizes[1] / 2;

  char* p = (char*)d_ws;
  auto carve = [&](size_t bytes){ void* r = (void*)p; p += (bytes + 511) & ~(size_t)511; return r; };
  unsigned short* bufA = (unsigned short*)carve((size_t)N*256*2);
  unsigned short* bufH = (unsigned short*)carve((size_t)N*256*2);
  unsigned short* bufB = (unsigned short*)carve((size_t)N*256*2);
  unsigned short* wt1  = (unsigned short*)carve(256*256*2);
  unsigned short* wt2  = (unsigned short*)carve(256*256*2);
  unsigned short* wt3  = (unsigned short*)carve(256*256*2);
  float* als   = (float*)carve((size_t)N*4*4);
  float* ald   = (float*)carve((size_t)N*4*4);
  int* rowptr  = (int*)carve((size_t)(N+1)*4);
  int* cursor  = (int*)carve((size_t)N*4);
  int* srcs    = (int*)carve((size_t)(E+N)*4);

  // CSR build
  hipMemsetAsync(cursor, 0, (size_t)N*4, stream);
  k_hist<<<2048, 256, 0, stream>>>(ei, E, N, cursor);
  k_scan<<<1, 1024, 0, stream>>>(cursor, rowptr, N);
  hipMemsetAsync(cursor, 0, (size_t)N*4, stream);
  k_scatter<<<2048, 256, 0, stream>>>(ei, E, N, rowptr, cursor, srcs);

  // input conversions
  int n4 = (N*256)/4;
  k_f32_to_bf16<<<(n4 + 255)/256, 256, 0, stream>>>(x, bufA, n4);
  k_transpose_w<<<256, 256, 0, stream>>>(W1, wt1);
  k_transpose_w<<<256, 256, 0, stream>>>(W2, wt2);
  k_transpose_w<<<256, 256, 0, stream>>>(W3, wt3);

  int gemm_grid  = N / 16;              // N divisible by 16 (50000)
  int nodeblocks = (N*64 + 255)/256;

  // layer 1
  k_gemm<<<gemm_grid, 1024, 0, stream>>>(bufA, wt1, bufH);
  k_al<<<nodeblocks, 256, 0, stream>>>(bufH, asrc1, adst1, als, ald, N);
  k_agg<0><<<nodeblocks, 256, 0, stream>>>(bufH, rowptr, srcs, als, ald, b1, bufB, nullptr, N);
  // layer 2
  k_gemm<<<gemm_grid, 1024, 0, stream>>>(bufB, wt2, bufH);
  k_al<<<nodeblocks, 256, 0, stream>>>(bufH, asrc2, adst2, als, ald, N);
  k_agg<0><<<nodeblocks, 256, 0, stream>>>(bufH, rowptr, srcs, als, ald, b2, bufA, nullptr, N);
  // layer 3
  k_gemm<<<gemm_grid, 1024, 0, stream>>>(bufA, wt3, bufH);
  k_al<<<nodeblocks, 256, 0, stream>>>(bufH, asrc3, adst3, als, ald, N);
  k_agg<1><<<nodeblocks, 256, 0, stream>>>(bufH, rowptr, srcs, als, ald, b3, nullptr, out, N);
}

// Round 2
// 529.291 us; speedup vs baseline: 1.3280x; 1.3280x over previous
//
#include <hip/hip_runtime.h>
#include <stdint.h>

typedef __bf16 bf16x8 __attribute__((ext_vector_type(8)));
typedef float f32x4 __attribute__((ext_vector_type(4)));

__device__ __forceinline__ unsigned short f2bf(float f){
  union { float f; unsigned u; } c; c.f = f;
  unsigned u = c.u;
  unsigned r = u + 0x7FFFu + ((u >> 16) & 1u);
  return (unsigned short)(r >> 16);
}
__device__ __forceinline__ float bf2f(unsigned short h){
  union { unsigned u; float f; } c; c.u = ((unsigned)h) << 16;
  return c.f;
}

// ---------------- CSR build (group edges by dst) ----------------
__global__ void k_hist(const int* __restrict__ ei, int E, int Nn, int* __restrict__ counts){
  int total = E + Nn;
  for (int e = blockIdx.x*blockDim.x + threadIdx.x; e < total; e += gridDim.x*blockDim.x){
    int d = (e < E) ? ei[E + e] : (e - E);
    atomicAdd(&counts[d], 1);
  }
}

__global__ __launch_bounds__(1024) void k_scan(const int* __restrict__ counts, int* __restrict__ rowptr, int n){
  __shared__ int wsum[17];
  __shared__ int carry_s;
  int tid = threadIdx.x, lane = tid & 63, wid = tid >> 6;
  if (tid == 0){ carry_s = 0; rowptr[0] = 0; }
  __syncthreads();
  for (int base = 0; base < n; base += 1024){
    int i = base + tid;
    int v = (i < n) ? counts[i] : 0;
    int iv = v;
    #pragma unroll
    for (int off = 1; off < 64; off <<= 1){
      int t = __shfl_up(iv, off, 64);
      if (lane >= off) iv += t;
    }
    if (lane == 63) wsum[wid] = iv;
    __syncthreads();
    if (tid == 0){
      int run = 0;
      for (int w = 0; w < 16; ++w){ int t = wsum[w]; wsum[w] = run; run += t; }
      wsum[16] = run;
    }
    __syncthreads();
    int outv = iv + wsum[wid] + carry_s;
    if (i < n) rowptr[i + 1] = outv;
    int total = wsum[16];
    __syncthreads();
    if (tid == 0) carry_s += total;
    __syncthreads();
  }
}

__global__ void k_scatter(const int* __restrict__ ei, int E, int Nn, const int* __restrict__ rowptr,
                          int* __restrict__ cursor, int* __restrict__ srcs){
  int total = E + Nn;
  for (int e = blockIdx.x*blockDim.x + threadIdx.x; e < total; e += gridDim.x*blockDim.x){
    int s, d;
    if (e < E){ s = ei[e]; d = ei[E + e]; } else { s = d = e - E; }
    int pos = rowptr[d] + atomicAdd(&cursor[d], 1);
    srcs[pos] = s;
  }
}

__global__ void k_transpose_w(const float* __restrict__ W, unsigned short* __restrict__ Wt){
  int t = blockIdx.x*blockDim.x + threadIdx.x; // 65536 threads
  int k = t >> 8, c = t & 255;
  Wt[c*256 + k] = f2bf(W[k*256 + c]);
}

// ---------------- fused GEMM + attention-logit epilogue ----------------
// [M,256] x [256,256] -> H [M,256] bf16, plus als/ald [M,4] f32.
// 256 threads = 4 waves; block covers 32 rows x 256 cols; wave w owns head w
// (cols w*64..w*64+63): 2 row-tiles x 4 col-tiles of 16x16x32 MFMA.
template<bool AF32>
__global__ __launch_bounds__(256) void k_gemm_fused(const void* __restrict__ Av,
                                                    const unsigned short* __restrict__ Wt,
                                                    const float* __restrict__ asrc,
                                                    const float* __restrict__ adst,
                                                    unsigned short* __restrict__ H,
                                                    float* __restrict__ als,
                                                    float* __restrict__ ald,
                                                    int Nn){
  int w = threadIdx.x >> 6;      // head 0..3
  int lane = threadIdx.x & 63;
  int r = lane & 15, kg = lane >> 4;
  int row0 = blockIdx.x * 32;

  int ra0 = row0 + r;       if (ra0 >= Nn) ra0 = Nn - 1;
  int ra1 = row0 + 16 + r;  if (ra1 >= Nn) ra1 = Nn - 1;

  const unsigned short* a16 = (const unsigned short*)Av;
  const float*          a32 = (const float*)Av;

  f32x4 acc[2][4] = {};

  #pragma unroll
  for (int k0 = 0; k0 < 256; k0 += 32){
    bf16x8 af[2];
    if (AF32){
      #pragma unroll
      for (int n = 0; n < 2; ++n){
        const float* ap = a32 + (size_t)(n ? ra1 : ra0)*256 + kg*8 + k0;
        float4 v0 = *reinterpret_cast<const float4*>(ap);
        float4 v1 = *reinterpret_cast<const float4*>(ap + 4);
        union { bf16x8 v; unsigned short s[8]; } u;
        u.s[0]=f2bf(v0.x); u.s[1]=f2bf(v0.y); u.s[2]=f2bf(v0.z); u.s[3]=f2bf(v0.w);
        u.s[4]=f2bf(v1.x); u.s[5]=f2bf(v1.y); u.s[6]=f2bf(v1.z); u.s[7]=f2bf(v1.w);
        af[n] = u.v;
      }
    } else {
      af[0] = *reinterpret_cast<const bf16x8*>(a16 + (size_t)ra0*256 + kg*8 + k0);
      af[1] = *reinterpret_cast<const bf16x8*>(a16 + (size_t)ra1*256 + kg*8 + k0);
    }
    #pragma unroll
    for (int c = 0; c < 4; ++c){
      bf16x8 bf = *reinterpret_cast<const bf16x8*>(Wt + (size_t)(w*64 + c*16 + r)*256 + kg*8 + k0);
      acc[0][c] = __builtin_amdgcn_mfma_f32_16x16x32_bf16(af[0], bf, acc[0][c], 0, 0, 0);
      acc[1][c] = __builtin_amdgcn_mfma_f32_16x16x32_bf16(af[1], bf, acc[1][c], 0, 0, 0);
    }
  }

  // store H (bf16). C layout: col = c*16 + r (r=lane&15), row = kg*4 + i.
  #pragma unroll
  for (int n = 0; n < 2; ++n){
    #pragma unroll
    for (int i = 0; i < 4; ++i){
      int row = row0 + n*16 + kg*4 + i;
      if (row < Nn){
        #pragma unroll
        for (int c = 0; c < 4; ++c)
          H[(size_t)row*256 + w*64 + c*16 + r] = f2bf(acc[n][c][i]);
      }
    }
  }

  // fused attention logits: als[row][w] = sum_d h[row][w*64+d]*asrc[w][d]
  float as_c[4], ad_c[4];
  #pragma unroll
  for (int c = 0; c < 4; ++c){
    as_c[c] = asrc[w*64 + c*16 + r];
    ad_c[c] = adst[w*64 + c*16 + r];
  }
  #pragma unroll
  for (int n = 0; n < 2; ++n){
    #pragma unroll
    for (int i = 0; i < 4; ++i){
      float ps = acc[n][0][i]*as_c[0] + acc[n][1][i]*as_c[1]
               + acc[n][2][i]*as_c[2] + acc[n][3][i]*as_c[3];
      float pd = acc[n][0][i]*ad_c[0] + acc[n][1][i]*ad_c[1]
               + acc[n][2][i]*ad_c[2] + acc[n][3][i]*ad_c[3];
      #pragma unroll
      for (int off = 1; off < 16; off <<= 1){
        ps += __shfl_xor(ps, off, 64);
        pd += __shfl_xor(pd, off, 64);
      }
      int row = row0 + n*16 + kg*4 + i;
      if (r == 0 && row < Nn){
        als[row*4 + w] = ps;
        ald[row*4 + w] = pd;
      }
    }
  }
}

// ---------------- aggregation: one wave per destination node ----------------
// MODE 0: concat heads, +bias, ELU, write bf16 activation [N,256]
// MODE 1: mean heads, +bias, log_softmax over 64 classes, write f32 [N,64]
template<int MODE>
__global__ void k_agg(const unsigned short* __restrict__ Hm, const int* __restrict__ rowptr,
                      const int* __restrict__ srcs, const float* __restrict__ als,
                      const float* __restrict__ ald, const float* __restrict__ bias,
                      unsigned short* __restrict__ actout, float* __restrict__ finalout, int Nn){
  int gid = blockIdx.x*blockDim.x + threadIdx.x;
  int node = gid >> 6, lane = gid & 63;
  if (node >= Nn) return;
  int hd = lane >> 4;
  int beg = rowptr[node], end = rowptr[node + 1];
  int deg = end - beg;
  float4 aldv = *reinterpret_cast<const float4*>(ald + node*4);
  float ald0 = aldv.x, ald1 = aldv.y, ald2 = aldv.z, ald3 = aldv.w;
  float aldh = (hd == 0) ? ald0 : (hd == 1) ? ald1 : (hd == 2) ? ald2 : ald3;

  // pass 1: per-head max of leaky_relu(als[src]+ald[node]) over edges
  float m0 = -1e30f, m1 = -1e30f, m2 = -1e30f, m3 = -1e30f;
  for (int jb = 0; jb < deg; jb += 64){
    int j = jb + lane;
    if (j < deg){
      int sj = srcs[beg + j];
      float4 a = *reinterpret_cast<const float4*>(als + sj*4);
      float l0 = a.x + ald0; l0 = l0 > 0.f ? l0 : 0.2f*l0; m0 = fmaxf(m0, l0);
      float l1 = a.y + ald1; l1 = l1 > 0.f ? l1 : 0.2f*l1; m1 = fmaxf(m1, l1);
      float l2 = a.z + ald2; l2 = l2 > 0.f ? l2 : 0.2f*l2; m2 = fmaxf(m2, l2);
      float l3 = a.w + ald3; l3 = l3 > 0.f ? l3 : 0.2f*l3; m3 = fmaxf(m3, l3);
    }
  }
  #pragma unroll
  for (int off = 1; off < 64; off <<= 1){
    m0 = fmaxf(m0, __shfl_xor(m0, off, 64));
    m1 = fmaxf(m1, __shfl_xor(m1, off, 64));
    m2 = fmaxf(m2, __shfl_xor(m2, off, 64));
    m3 = fmaxf(m3, __shfl_xor(m3, off, 64));
  }
  float mh = (hd == 0) ? m0 : (hd == 1) ? m1 : (hd == 2) ? m2 : m3;

  // pass 2: accumulate w*h and denominator (unnormalized)
  float s = 0.f, acc0 = 0.f, acc1 = 0.f, acc2 = 0.f, acc3 = 0.f;
  for (int cb = 0; cb < deg; cb += 64){
    int chunk = min(64, deg - cb);
    int mysrc = 0;
    if (cb + lane < deg) mysrc = srcs[beg + cb + lane];
    for (int j = 0; j < chunk; ++j){
      int sj = __shfl(mysrc, j, 64);
      float l = als[sj*4 + hd] + aldh; l = l > 0.f ? l : 0.2f*l;
      float w = __expf(l - mh);
      s += w;
      ushort4 hv = *reinterpret_cast<const ushort4*>(Hm + (size_t)sj*256 + lane*4);
      acc0 += w*bf2f(hv.x); acc1 += w*bf2f(hv.y);
      acc2 += w*bf2f(hv.z); acc3 += w*bf2f(hv.w);
    }
  }
  float inv = 1.f / s;

  if (MODE == 0){
    float4 bv = *reinterpret_cast<const float4*>(bias + lane*4);
    float o0 = acc0*inv + bv.x, o1 = acc1*inv + bv.y, o2 = acc2*inv + bv.z, o3 = acc3*inv + bv.w;
    o0 = o0 > 0.f ? o0 : __expf(o0) - 1.f;
    o1 = o1 > 0.f ? o1 : __expf(o1) - 1.f;
    o2 = o2 > 0.f ? o2 : __expf(o2) - 1.f;
    o3 = o3 > 0.f ? o3 : __expf(o3) - 1.f;
    ushort4 o; o.x = f2bf(o0); o.y = f2bf(o1); o.z = f2bf(o2); o.w = f2bf(o3);
    *reinterpret_cast<ushort4*>(actout + (size_t)node*256 + lane*4) = o;
  } else {
    // mean over heads: lanes L, L^16, L^32, L^48 hold same d, different head
    float v0 = acc0*inv, v1 = acc1*inv, v2 = acc2*inv, v3 = acc3*inv;
    #pragma unroll
    for (int off = 16; off < 64; off <<= 1){
      v0 += __shfl_xor(v0, off, 64);
      v1 += __shfl_xor(v1, off, 64);
      v2 += __shfl_xor(v2, off, 64);
      v3 += __shfl_xor(v3, off, 64);
    }
    int d0 = (lane & 15)*4;
    float4 bv = *reinterpret_cast<const float4*>(bias + d0);
    v0 = v0*0.25f + bv.x; v1 = v1*0.25f + bv.y; v2 = v2*0.25f + bv.z; v3 = v3*0.25f + bv.w;
    float mx = fmaxf(fmaxf(v0, v1), fmaxf(v2, v3));
    #pragma unroll
    for (int off = 1; off < 16; off <<= 1) mx = fmaxf(mx, __shfl_xor(mx, off, 64));
    float se = __expf(v0 - mx) + __expf(v1 - mx) + __expf(v2 - mx) + __expf(v3 - mx);
    #pragma unroll
    for (int off = 1; off < 16; off <<= 1) se += __shfl_xor(se, off, 64);
    float lse = mx + __logf(se);
    if (lane < 16){
      float4 o; o.x = v0 - lse; o.y = v1 - lse; o.z = v2 - lse; o.w = v3 - lse;
      *reinterpret_cast<float4*>(finalout + (size_t)node*64 + d0) = o;
    }
  }
}

extern "C" void kernel_launch(void* const* d_in, const int* in_sizes, int n_in,
                              void* d_out, int out_size, void* d_ws, size_t ws_size,
                              hipStream_t stream){
  const float* x     = (const float*)d_in[0];
  const int*   ei    = (const int*)  d_in[1];
  const float* W1    = (const float*)d_in[2];
  const float* asrc1 = (const float*)d_in[3];
  const float* adst1 = (const float*)d_in[4];
  const float* b1    = (const float*)d_in[5];
  const float* W2    = (const float*)d_in[6];
  const float* asrc2 = (const float*)d_in[7];
  const float* adst2 = (const float*)d_in[8];
  const float* b2    = (const float*)d_in[9];
  const float* W3    = (const float*)d_in[10];
  const float* asrc3 = (const float*)d_in[11];
  const float* adst3 = (const float*)d_in[12];
  const float* b3    = (const float*)d_in[13];
  float* out = (float*)d_out;

  int N = in_sizes[0] / 256;
  int E = in_sizes[1] / 2;

  char* p = (char*)d_ws;
  auto carve = [&](size_t bytes){ void* r = (void*)p; p += (bytes + 511) & ~(size_t)511; return r; };
  unsigned short* bufA = (unsigned short*)carve((size_t)N*256*2);
  unsigned short* bufH = (unsigned short*)carve((size_t)N*256*2);
  unsigned short* bufB = (unsigned short*)carve((size_t)N*256*2);
  unsigned short* wt1  = (unsigned short*)carve(256*256*2);
  unsigned short* wt2  = (unsigned short*)carve(256*256*2);
  unsigned short* wt3  = (unsigned short*)carve(256*256*2);
  float* als   = (float*)carve((size_t)N*4*4);
  float* ald   = (float*)carve((size_t)N*4*4);
  int* rowptr  = (int*)carve((size_t)(N+1)*4);
  int* cursor  = (int*)carve((size_t)N*4);
  int* srcs    = (int*)carve((size_t)(E+N)*4);

  // CSR build
  hipMemsetAsync(cursor, 0, (size_t)N*4, stream);
  k_hist<<<2048, 256, 0, stream>>>(ei, E, N, cursor);
  k_scan<<<1, 1024, 0, stream>>>(cursor, rowptr, N);
  hipMemsetAsync(cursor, 0, (size_t)N*4, stream);
  k_scatter<<<2048, 256, 0, stream>>>(ei, E, N, rowptr, cursor, srcs);

  // weight transposes (tiny)
  k_transpose_w<<<256, 256, 0, stream>>>(W1, wt1);
  k_transpose_w<<<256, 256, 0, stream>>>(W2, wt2);
  k_transpose_w<<<256, 256, 0, stream>>>(W3, wt3);

  int gemm_grid  = (N + 31) / 32;
  int nodeblocks = (N*64 + 255)/256;

  // layer 1 (A = x in f32)
  k_gemm_fused<true><<<gemm_grid, 256, 0, stream>>>(x, wt1, asrc1, adst1, bufH, als, ald, N);
  k_agg<0><<<nodeblocks, 256, 0, stream>>>(bufH, rowptr, srcs, als, ald, b1, bufB, nullptr, N);
  // layer 2
  k_gemm_fused<false><<<gemm_grid, 256, 0, stream>>>(bufB, wt2, asrc2, adst2, bufH, als, ald, N);
  k_agg<0><<<nodeblocks, 256, 0, stream>>>(bufH, rowptr, srcs, als, ald, b2, bufA, nullptr, N);
  // layer 3
  k_gemm_fused<false><<<gemm_grid, 256, 0, stream>>>(bufA, wt3, asrc3, adst3, bufH, als, ald, N);
  k_agg<1><<<nodeblocks, 256, 0, stream>>>(bufH, rowptr, srcs, als, ald, b3, nullptr, out, N);
}

// Round 3
// 527.726 us; speedup vs baseline: 1.3319x; 1.0030x over previous
//
#include <hip/hip_runtime.h>
#include <stdint.h>

typedef __bf16 bf16x8 __attribute__((ext_vector_type(8)));
typedef float f32x4 __attribute__((ext_vector_type(4)));
typedef unsigned short u16x8 __attribute__((ext_vector_type(8)));

__device__ __forceinline__ unsigned short f2bf(float f){
  union { float f; unsigned u; } c; c.f = f;
  unsigned u = c.u;
  unsigned r = u + 0x7FFFu + ((u >> 16) & 1u);
  return (unsigned short)(r >> 16);
}
__device__ __forceinline__ float bf2f(unsigned short h){
  union { unsigned u; float f; } c; c.u = ((unsigned)h) << 16;
  return c.f;
}

// ---------------- CSR build (group edges by dst) ----------------
__global__ void k_hist(const int* __restrict__ ei, int E, int Nn, int* __restrict__ counts){
  int total = E + Nn;
  for (int e = blockIdx.x*blockDim.x + threadIdx.x; e < total; e += gridDim.x*blockDim.x){
    int d = (e < E) ? ei[E + e] : (e - E);
    atomicAdd(&counts[d], 1);
  }
}

// block-local inclusive scan of 1024 elements; rowptr[i+1] = local scan, bsum[b] = block total
__global__ __launch_bounds__(1024) void k_scan1(const int* __restrict__ counts, int* __restrict__ rowptr,
                                                int* __restrict__ bsum, int n){
  __shared__ int wsum[17];
  int tid = threadIdx.x, lane = tid & 63, wid = tid >> 6;
  int i = blockIdx.x*1024 + tid;
  int v = (i < n) ? counts[i] : 0;
  int iv = v;
  #pragma unroll
  for (int off = 1; off < 64; off <<= 1){
    int t = __shfl_up(iv, off, 64);
    if (lane >= off) iv += t;
  }
  if (lane == 63) wsum[wid] = iv;
  __syncthreads();
  if (tid == 0){
    int run = 0;
    for (int w = 0; w < 16; ++w){ int t = wsum[w]; wsum[w] = run; run += t; }
    wsum[16] = run;
  }
  __syncthreads();
  if (i < n) rowptr[i + 1] = iv + wsum[wid];
  if (tid == 0) bsum[blockIdx.x] = wsum[16];
}

// scan of block totals (nb <= 1024), in place -> exclusive offsets
__global__ __launch_bounds__(1024) void k_scan2(int* __restrict__ bsum, int nb){
  __shared__ int wsum[17];
  int tid = threadIdx.x, lane = tid & 63, wid = tid >> 6;
  int v = (tid < nb) ? bsum[tid] : 0;
  int iv = v;
  #pragma unroll
  for (int off = 1; off < 64; off <<= 1){
    int t = __shfl_up(iv, off, 64);
    if (lane >= off) iv += t;
  }
  if (lane == 63) wsum[wid] = iv;
  __syncthreads();
  if (tid == 0){
    int run = 0;
    for (int w = 0; w < 16; ++w){ int t = wsum[w]; wsum[w] = run; run += t; }
  }
  __syncthreads();
  if (tid < nb) bsum[tid] = iv + wsum[wid] - v;   // exclusive
}

__global__ void k_scan3(int* __restrict__ rowptr, const int* __restrict__ bsum, int n){
  int i = blockIdx.x*blockDim.x + threadIdx.x;
  if (i == 0) rowptr[0] = 0;
  if (i < n) rowptr[i + 1] += bsum[i >> 10];
}

__global__ void k_scatter(const int* __restrict__ ei, int E, int Nn, const int* __restrict__ rowptr,
                          int* __restrict__ cursor, int* __restrict__ srcs){
  int total = E + Nn;
  for (int e = blockIdx.x*blockDim.x + threadIdx.x; e < total; e += gridDim.x*blockDim.x){
    int s, d;
    if (e < E){ s = ei[e]; d = ei[E + e]; } else { s = d = e - E; }
    int pos = rowptr[d] + atomicAdd(&cursor[d], 1);
    srcs[pos] = s;
  }
}

__global__ void k_transpose_w(const float* __restrict__ W, unsigned short* __restrict__ Wt){
  int t = blockIdx.x*blockDim.x + threadIdx.x; // 65536 threads
  int k = t >> 8, c = t & 255;
  Wt[c*256 + k] = f2bf(W[k*256 + c]);
}

// ---------------- fused GEMM + attention-logit epilogue ----------------
template<bool AF32>
__global__ __launch_bounds__(256) void k_gemm_fused(const void* __restrict__ Av,
                                                    const unsigned short* __restrict__ Wt,
                                                    const float* __restrict__ asrc,
                                                    const float* __restrict__ adst,
                                                    unsigned short* __restrict__ H,
                                                    float* __restrict__ als,
                                                    float* __restrict__ ald,
                                                    int Nn){
  int w = threadIdx.x >> 6;      // head 0..3
  int lane = threadIdx.x & 63;
  int r = lane & 15, kg = lane >> 4;
  int row0 = blockIdx.x * 32;

  int ra0 = row0 + r;       if (ra0 >= Nn) ra0 = Nn - 1;
  int ra1 = row0 + 16 + r;  if (ra1 >= Nn) ra1 = Nn - 1;

  const unsigned short* a16 = (const unsigned short*)Av;
  const float*          a32 = (const float*)Av;

  f32x4 acc[2][4] = {};

  #pragma unroll
  for (int k0 = 0; k0 < 256; k0 += 32){
    bf16x8 af[2];
    if (AF32){
      #pragma unroll
      for (int n = 0; n < 2; ++n){
        const float* ap = a32 + (size_t)(n ? ra1 : ra0)*256 + kg*8 + k0;
        float4 v0 = *reinterpret_cast<const float4*>(ap);
        float4 v1 = *reinterpret_cast<const float4*>(ap + 4);
        union { bf16x8 v; unsigned short s[8]; } u;
        u.s[0]=f2bf(v0.x); u.s[1]=f2bf(v0.y); u.s[2]=f2bf(v0.z); u.s[3]=f2bf(v0.w);
        u.s[4]=f2bf(v1.x); u.s[5]=f2bf(v1.y); u.s[6]=f2bf(v1.z); u.s[7]=f2bf(v1.w);
        af[n] = u.v;
      }
    } else {
      af[0] = *reinterpret_cast<const bf16x8*>(a16 + (size_t)ra0*256 + kg*8 + k0);
      af[1] = *reinterpret_cast<const bf16x8*>(a16 + (size_t)ra1*256 + kg*8 + k0);
    }
    #pragma unroll
    for (int c = 0; c < 4; ++c){
      bf16x8 bf = *reinterpret_cast<const bf16x8*>(Wt + (size_t)(w*64 + c*16 + r)*256 + kg*8 + k0);
      acc[0][c] = __builtin_amdgcn_mfma_f32_16x16x32_bf16(af[0], bf, acc[0][c], 0, 0, 0);
      acc[1][c] = __builtin_amdgcn_mfma_f32_16x16x32_bf16(af[1], bf, acc[1][c], 0, 0, 0);
    }
  }

  #pragma unroll
  for (int n = 0; n < 2; ++n){
    #pragma unroll
    for (int i = 0; i < 4; ++i){
      int row = row0 + n*16 + kg*4 + i;
      if (row < Nn){
        #pragma unroll
        for (int c = 0; c < 4; ++c)
          H[(size_t)row*256 + w*64 + c*16 + r] = f2bf(acc[n][c][i]);
      }
    }
  }

  float as_c[4], ad_c[4];
  #pragma unroll
  for (int c = 0; c < 4; ++c){
    as_c[c] = asrc[w*64 + c*16 + r];
    ad_c[c] = adst[w*64 + c*16 + r];
  }
  #pragma unroll
  for (int n = 0; n < 2; ++n){
    #pragma unroll
    for (int i = 0; i < 4; ++i){
      float ps = acc[n][0][i]*as_c[0] + acc[n][1][i]*as_c[1]
               + acc[n][2][i]*as_c[2] + acc[n][3][i]*as_c[3];
      float pd = acc[n][0][i]*ad_c[0] + acc[n][1][i]*ad_c[1]
               + acc[n][2][i]*ad_c[2] + acc[n][3][i]*ad_c[3];
      #pragma unroll
      for (int off = 1; off < 16; off <<= 1){
        ps += __shfl_xor(ps, off, 64);
        pd += __shfl_xor(pd, off, 64);
      }
      int row = row0 + n*16 + kg*4 + i;
      if (r == 0 && row < Nn){
        als[row*4 + w] = ps;
        ald[row*4 + w] = pd;
      }
    }
  }
}

// ---------------- attention weights: per-node segment softmax numerators ----------------
// writes wbuf[pos] = float4 exp-weights per edge, sbuf[node] = float4 1/denominator
__global__ void k_attw(const int* __restrict__ rowptr, const int* __restrict__ srcs,
                       const float* __restrict__ als, const float* __restrict__ ald,
                       float* __restrict__ wbuf, float* __restrict__ sbuf, int Nn){
  int gid = blockIdx.x*blockDim.x + threadIdx.x;
  int node = gid >> 6, lane = gid & 63;
  if (node >= Nn) return;
  int beg = rowptr[node], deg = rowptr[node + 1] - beg;
  float4 adv = *reinterpret_cast<const float4*>(ald + node*4);

  float f0=0.f, f1=0.f, f2=0.f, f3=0.f;   // first-batch logit cache
  float m0=-1e30f, m1=-1e30f, m2=-1e30f, m3=-1e30f;
  for (int jb = 0; jb < deg; jb += 64){
    int j = jb + lane;
    float t0=-1e30f, t1=-1e30f, t2=-1e30f, t3=-1e30f;
    if (j < deg){
      int sj = srcs[beg + j];
      float4 a = *reinterpret_cast<const float4*>(als + sj*4);
      t0 = a.x + adv.x; t0 = t0 > 0.f ? t0 : 0.2f*t0;
      t1 = a.y + adv.y; t1 = t1 > 0.f ? t1 : 0.2f*t1;
      t2 = a.z + adv.z; t2 = t2 > 0.f ? t2 : 0.2f*t2;
      t3 = a.w + adv.w; t3 = t3 > 0.f ? t3 : 0.2f*t3;
    }
    if (jb == 0){ f0 = t0; f1 = t1; f2 = t2; f3 = t3; }
    m0 = fmaxf(m0, t0); m1 = fmaxf(m1, t1);
    m2 = fmaxf(m2, t2); m3 = fmaxf(m3, t3);
  }
  #pragma unroll
  for (int off = 1; off < 64; off <<= 1){
    m0 = fmaxf(m0, __shfl_xor(m0, off, 64));
    m1 = fmaxf(m1, __shfl_xor(m1, off, 64));
    m2 = fmaxf(m2, __shfl_xor(m2, off, 64));
    m3 = fmaxf(m3, __shfl_xor(m3, off, 64));
  }

  float s0=0.f, s1=0.f, s2=0.f, s3=0.f;
  for (int jb = 0; jb < deg; jb += 64){
    int j = jb + lane;
    if (j < deg){
      float t0, t1, t2, t3;
      if (jb == 0){ t0 = f0; t1 = f1; t2 = f2; t3 = f3; }
      else {
        int sj = srcs[beg + j];
        float4 a = *reinterpret_cast<const float4*>(als + sj*4);
        t0 = a.x + adv.x; t0 = t0 > 0.f ? t0 : 0.2f*t0;
        t1 = a.y + adv.y; t1 = t1 > 0.f ? t1 : 0.2f*t1;
        t2 = a.z + adv.z; t2 = t2 > 0.f ? t2 : 0.2f*t2;
        t3 = a.w + adv.w; t3 = t3 > 0.f ? t3 : 0.2f*t3;
      }
      float w0 = __expf(t0 - m0), w1 = __expf(t1 - m1);
      float w2 = __expf(t2 - m2), w3 = __expf(t3 - m3);
      s0 += w0; s1 += w1; s2 += w2; s3 += w3;
      float4 wv; wv.x = w0; wv.y = w1; wv.z = w2; wv.w = w3;
      *reinterpret_cast<float4*>(wbuf + (size_t)(beg + j)*4) = wv;
    }
  }
  #pragma unroll
  for (int off = 1; off < 64; off <<= 1){
    s0 += __shfl_xor(s0, off, 64);
    s1 += __shfl_xor(s1, off, 64);
    s2 += __shfl_xor(s2, off, 64);
    s3 += __shfl_xor(s3, off, 64);
  }
  if (lane == 0){
    float4 iv; iv.x = 1.f/s0; iv.y = 1.f/s1; iv.z = 1.f/s2; iv.w = 1.f/s3;
    *reinterpret_cast<float4*>(sbuf + node*4) = iv;
  }
}

// ---------------- weighted gather: one wave per destination node ----------------
// 2 rows per load-instruction (32 lanes x 16B each), unroll x4 -> 8 edges in flight.
// MODE 0: concat heads, +bias, ELU, write bf16 activation [N,256]
// MODE 1: mean heads, +bias, log_softmax over 64 classes, write f32 [N,64]
template<int MODE>
__global__ void k_gather(const unsigned short* __restrict__ Hm, const int* __restrict__ rowptr,
                         const int* __restrict__ srcs, const float* __restrict__ wbuf,
                         const float* __restrict__ sbuf, const float* __restrict__ bias,
                         unsigned short* __restrict__ actout, float* __restrict__ finalout, int Nn){
  int gid = blockIdx.x*blockDim.x + threadIdx.x;
  int node = gid >> 6, lane = gid & 63;
  if (node >= Nn) return;
  int half = lane >> 5;          // which edge of the pair
  int l32  = lane & 31;
  int fbase = l32 * 8;           // features fbase..fbase+7
  int hd = l32 >> 3;             // head of those features
  unsigned voff_feat = (unsigned)(l32 * 16);           // bytes into the 512B row
  unsigned vwoff = (unsigned)((half << 4) + (hd << 2)); // bytes into wbuf pair

  int beg = rowptr[node], deg = rowptr[node + 1] - beg;

  float acc[4][8];
  #pragma unroll
  for (int u = 0; u < 4; ++u)
    #pragma unroll
    for (int i = 0; i < 8; ++i) acc[u][i] = 0.f;

  const char* Hb = (const char*)Hm;
  const char* Wb = (const char*)wbuf;

  for (int cb = 0; cb < deg; cb += 64){
    int chunk = min(64, deg - cb);
    int mysrc = (cb + lane < deg) ? srcs[beg + cb + lane] : 0;
    int jmax8 = chunk & ~7;
    int j = 0;
    for (; j < jmax8; j += 8){
      #pragma unroll
      for (int u = 0; u < 4; ++u){
        int e0 = j + 2*u;
        int sA = __builtin_amdgcn_readlane(mysrc, e0);
        int sB = __builtin_amdgcn_readlane(mysrc, e0 + 1);
        unsigned hoff = (unsigned)(half ? sB : sA)*512u + voff_feat;
        uint4 hw = *reinterpret_cast<const uint4*>(Hb + hoff);
        float wgt = *reinterpret_cast<const float*>(Wb + (((unsigned)(beg + cb + e0)) << 4) + vwoff);
        float h0 = __uint_as_float(hw.x << 16);
        float h1 = __uint_as_float(hw.x & 0xffff0000u);
        float h2 = __uint_as_float(hw.y << 16);
        float h3 = __uint_as_float(hw.y & 0xffff0000u);
        float h4 = __uint_as_float(hw.z << 16);
        float h5 = __uint_as_float(hw.z & 0xffff0000u);
        float h6 = __uint_as_float(hw.w << 16);
        float h7 = __uint_as_float(hw.w & 0xffff0000u);
        acc[u][0] = fmaf(wgt, h0, acc[u][0]);
        acc[u][1] = fmaf(wgt, h1, acc[u][1]);
        acc[u][2] = fmaf(wgt, h2, acc[u][2]);
        acc[u][3] = fmaf(wgt, h3, acc[u][3]);
        acc[u][4] = fmaf(wgt, h4, acc[u][4]);
        acc[u][5] = fmaf(wgt, h5, acc[u][5]);
        acc[u][6] = fmaf(wgt, h6, acc[u][6]);
        acc[u][7] = fmaf(wgt, h7, acc[u][7]);
      }
    }
    for (; j < chunk; j += 2){
      int eA = j;
      int eB = (j + 1 < chunk) ? (j + 1) : (chunk - 1);
      int sA = __builtin_amdgcn_readlane(mysrc, eA);
      int sB = __builtin_amdgcn_readlane(mysrc, eB);
      unsigned hoff = (unsigned)(half ? sB : sA)*512u + voff_feat;
      uint4 hw = *reinterpret_cast<const uint4*>(Hb + hoff);
      int ew = half ? eB : eA;
      float wgt = *reinterpret_cast<const float*>(Wb + (((unsigned)(beg + cb + ew)) << 4) + (unsigned)(hd << 2));
      if (j + half >= chunk) wgt = 0.f;
      float h0 = __uint_as_float(hw.x << 16);
      float h1 = __uint_as_float(hw.x & 0xffff0000u);
      float h2 = __uint_as_float(hw.y << 16);
      float h3 = __uint_as_float(hw.y & 0xffff0000u);
      float h4 = __uint_as_float(hw.z << 16);
      float h5 = __uint_as_float(hw.z & 0xffff0000u);
      float h6 = __uint_as_float(hw.w << 16);
      float h7 = __uint_as_float(hw.w & 0xffff0000u);
      acc[0][0] = fmaf(wgt, h0, acc[0][0]);
      acc[0][1] = fmaf(wgt, h1, acc[0][1]);
      acc[0][2] = fmaf(wgt, h2, acc[0][2]);
      acc[0][3] = fmaf(wgt, h3, acc[0][3]);
      acc[0][4] = fmaf(wgt, h4, acc[0][4]);
      acc[0][5] = fmaf(wgt, h5, acc[0][5]);
      acc[0][6] = fmaf(wgt, h6, acc[0][6]);
      acc[0][7] = fmaf(wgt, h7, acc[0][7]);
    }
  }

  // fold 4 sets + the two halves
  float accf[8];
  #pragma unroll
  for (int i = 0; i < 8; ++i){
    float t = acc[0][i] + acc[1][i] + acc[2][i] + acc[3][i];
    t += __shfl_xor(t, 32, 64);
    accf[i] = t;
  }
  float inv = sbuf[node*4 + hd];

  if (MODE == 0){
    if (lane < 32){
      float4 b0 = *reinterpret_cast<const float4*>(bias + fbase);
      float4 b1 = *reinterpret_cast<const float4*>(bias + fbase + 4);
      float o[8];
      o[0] = accf[0]*inv + b0.x; o[1] = accf[1]*inv + b0.y;
      o[2] = accf[2]*inv + b0.z; o[3] = accf[3]*inv + b0.w;
      o[4] = accf[4]*inv + b1.x; o[5] = accf[5]*inv + b1.y;
      o[6] = accf[6]*inv + b1.z; o[7] = accf[7]*inv + b1.w;
      u16x8 pk;
      #pragma unroll
      for (int i = 0; i < 8; ++i){
        float v = o[i];
        v = v > 0.f ? v : __expf(v) - 1.f;
        pk[i] = f2bf(v);
      }
      *reinterpret_cast<u16x8*>(actout + (size_t)node*256 + fbase) = pk;
    }
  } else {
    float v[8];
    #pragma unroll
    for (int i = 0; i < 8; ++i){
      float t = accf[i]*inv;
      t += __shfl_xor(t, 8, 64);
      t += __shfl_xor(t, 16, 64);
      v[i] = t;
    }
    int k = l32 & 7;               // dim block 0..7 (dims k*8..k*8+7)
    float4 b0 = *reinterpret_cast<const float4*>(bias + k*8);
    float4 b1 = *reinterpret_cast<const float4*>(bias + k*8 + 4);
    v[0] = v[0]*0.25f + b0.x; v[1] = v[1]*0.25f + b0.y;
    v[2] = v[2]*0.25f + b0.z; v[3] = v[3]*0.25f + b0.w;
    v[4] = v[4]*0.25f + b1.x; v[5] = v[5]*0.25f + b1.y;
    v[6] = v[6]*0.25f + b1.z; v[7] = v[7]*0.25f + b1.w;
    float mx = v[0];
    #pragma unroll
    for (int i = 1; i < 8; ++i) mx = fmaxf(mx, v[i]);
    #pragma unroll
    for (int off = 1; off < 8; off <<= 1) mx = fmaxf(mx, __shfl_xor(mx, off, 64));
    float se = 0.f;
    #pragma unroll
    for (int i = 0; i < 8; ++i) se += __expf(v[i] - mx);
    #pragma unroll
    for (int off = 1; off < 8; off <<= 1) se += __shfl_xor(se, off, 64);
    float lse = mx + __logf(se);
    if (lane < 8){
      float4 o0, o1;
      o0.x = v[0]-lse; o0.y = v[1]-lse; o0.z = v[2]-lse; o0.w = v[3]-lse;
      o1.x = v[4]-lse; o1.y = v[5]-lse; o1.z = v[6]-lse; o1.w = v[7]-lse;
      float* dst = finalout + (size_t)node*64 + lane*8;
      *reinterpret_cast<float4*>(dst)     = o0;
      *reinterpret_cast<float4*>(dst + 4) = o1;
    }
  }
}

extern "C" void kernel_launch(void* const* d_in, const int* in_sizes, int n_in,
                              void* d_out, int out_size, void* d_ws, size_t ws_size,
                              hipStream_t stream){
  const float* x     = (const float*)d_in[0];
  const int*   ei    = (const int*)  d_in[1];
  const float* W1    = (const float*)d_in[2];
  const float* asrc1 = (const float*)d_in[3];
  const float* adst1 = (const float*)d_in[4];
  const float* b1    = (const float*)d_in[5];
  const float* W2    = (const float*)d_in[6];
  const float* asrc2 = (const float*)d_in[7];
  const float* adst2 = (const float*)d_in[8];
  const float* b2    = (const float*)d_in[9];
  const float* W3    = (const float*)d_in[10];
  const float* asrc3 = (const float*)d_in[11];
  const float* adst3 = (const float*)d_in[12];
  const float* b3    = (const float*)d_in[13];
  float* out = (float*)d_out;

  int N = in_sizes[0] / 256;
  int E = in_sizes[1] / 2;

  char* p = (char*)d_ws;
  auto carve = [&](size_t bytes){ void* r = (void*)p; p += (bytes + 511) & ~(size_t)511; return r; };
  unsigned short* bufA = (unsigned short*)carve((size_t)N*256*2);
  unsigned short* bufH = (unsigned short*)carve((size_t)N*256*2);
  unsigned short* bufB = (unsigned short*)carve((size_t)N*256*2);
  unsigned short* wt1  = (unsigned short*)carve(256*256*2);
  unsigned short* wt2  = (unsigned short*)carve(256*256*2);
  unsigned short* wt3  = (unsigned short*)carve(256*256*2);
  float* als   = (float*)carve((size_t)N*4*4);
  float* ald   = (float*)carve((size_t)N*4*4);
  float* sbuf  = (float*)carve((size_t)N*4*4);
  int* rowptr  = (int*)carve((size_t)(N+1)*4);
  int* cursor  = (int*)carve((size_t)N*4);
  int* bsum    = (int*)carve((size_t)1024*4);
  int* srcs    = (int*)carve((size_t)(E+N)*4);

  // wbuf overlays: (E+N)*16B + pad fits in a 25.6MB activation buffer (13.6MB needed)
  float* wbuf1 = (float*)bufA;   // bufA unused during layer 1 (x read directly)
  float* wbuf2 = (float*)bufB;   // bufB dead after gemm2 consumed it
  float* wbuf3 = (float*)bufB;   // still dead in layer 3

  // CSR build
  hipMemsetAsync(cursor, 0, (size_t)N*4, stream);
  k_hist<<<2048, 256, 0, stream>>>(ei, E, N, cursor);
  int nb = (N + 1023) / 1024;
  k_scan1<<<nb, 1024, 0, stream>>>(cursor, rowptr, bsum, N);
  k_scan2<<<1, 1024, 0, stream>>>(bsum, nb);
  k_scan3<<<(N + 255)/256, 256, 0, stream>>>(rowptr, bsum, N);
  hipMemsetAsync(cursor, 0, (size_t)N*4, stream);
  k_scatter<<<2048, 256, 0, stream>>>(ei, E, N, rowptr, cursor, srcs);

  // weight transposes (tiny)
  k_transpose_w<<<256, 256, 0, stream>>>(W1, wt1);
  k_transpose_w<<<256, 256, 0, stream>>>(W2, wt2);
  k_transpose_w<<<256, 256, 0, stream>>>(W3, wt3);

  int gemm_grid  = (N + 31) / 32;
  int nodeblocks = (N*64 + 255)/256;

  // layer 1 (A = x in f32)
  k_gemm_fused<true><<<gemm_grid, 256, 0, stream>>>(x, wt1, asrc1, adst1, bufH, als, ald, N);
  k_attw<<<nodeblocks, 256, 0, stream>>>(rowptr, srcs, als, ald, wbuf1, sbuf, N);
  k_gather<0><<<nodeblocks, 256, 0, stream>>>(bufH, rowptr, srcs, wbuf1, sbuf, b1, bufB, nullptr, N);
  // layer 2
  k_gemm_fused<false><<<gemm_grid, 256, 0, stream>>>(bufB, wt2, asrc2, adst2, bufH, als, ald, N);
  k_attw<<<nodeblocks, 256, 0, stream>>>(rowptr, srcs, als, ald, wbuf2, sbuf, N);
  k_gather<0><<<nodeblocks, 256, 0, stream>>>(bufH, rowptr, srcs, wbuf2, sbuf, b2, bufA, nullptr, N);
  // layer 3
  k_gemm_fused<false><<<gemm_grid, 256, 0, stream>>>(bufA, wt3, asrc3, adst3, bufH, als, ald, N);
  k_attw<<<nodeblocks, 256, 0, stream>>>(rowptr, srcs, als, ald, wbuf3, sbuf, N);
  k_gather<1><<<nodeblocks, 256, 0, stream>>>(bufH, rowptr, srcs, wbuf3, sbuf, b3, nullptr, out, N);
}

// Round 4
// 425.372 us; speedup vs baseline: 1.6524x; 1.2406x over previous
//
#include <hip/hip_runtime.h>
#include <stdint.h>

typedef __bf16 bf16x8 __attribute__((ext_vector_type(8)));
typedef float f32x4 __attribute__((ext_vector_type(4)));
typedef unsigned short u16x8 __attribute__((ext_vector_type(8)));

__device__ __forceinline__ unsigned short f2bf(float f){
  union { float f; unsigned u; } c; c.f = f;
  unsigned u = c.u;
  unsigned r = u + 0x7FFFu + ((u >> 16) & 1u);
  return (unsigned short)(r >> 16);
}

// ---------------- CSR build (group edges by dst) ----------------
__global__ void k_hist(const int* __restrict__ ei, int E, int Nn, int* __restrict__ counts){
  int total = E + Nn;
  for (int e = blockIdx.x*blockDim.x + threadIdx.x; e < total; e += gridDim.x*blockDim.x){
    int d = (e < E) ? ei[E + e] : (e - E);
    atomicAdd(&counts[d], 1);
  }
}

__global__ __launch_bounds__(1024) void k_scan1(const int* __restrict__ counts, int* __restrict__ rowptr,
                                                int* __restrict__ bsum, int n){
  __shared__ int wsum[17];
  int tid = threadIdx.x, lane = tid & 63, wid = tid >> 6;
  int i = blockIdx.x*1024 + tid;
  int v = (i < n) ? counts[i] : 0;
  int iv = v;
  #pragma unroll
  for (int off = 1; off < 64; off <<= 1){
    int t = __shfl_up(iv, off, 64);
    if (lane >= off) iv += t;
  }
  if (lane == 63) wsum[wid] = iv;
  __syncthreads();
  if (tid == 0){
    int run = 0;
    for (int w = 0; w < 16; ++w){ int t = wsum[w]; wsum[w] = run; run += t; }
    wsum[16] = run;
  }
  __syncthreads();
  if (i < n) rowptr[i + 1] = iv + wsum[wid];
  if (tid == 0) bsum[blockIdx.x] = wsum[16];
}

__global__ __launch_bounds__(1024) void k_scan2(int* __restrict__ bsum, int nb){
  __shared__ int wsum[17];
  int tid = threadIdx.x, lane = tid & 63, wid = tid >> 6;
  int v = (tid < nb) ? bsum[tid] : 0;
  int iv = v;
  #pragma unroll
  for (int off = 1; off < 64; off <<= 1){
    int t = __shfl_up(iv, off, 64);
    if (lane >= off) iv += t;
  }
  if (lane == 63) wsum[wid] = iv;
  __syncthreads();
  if (tid == 0){
    int run = 0;
    for (int w = 0; w < 16; ++w){ int t = wsum[w]; wsum[w] = run; run += t; }
  }
  __syncthreads();
  if (tid < nb) bsum[tid] = iv + wsum[wid] - v;   // exclusive
}

__global__ void k_scan3(int* __restrict__ rowptr, const int* __restrict__ bsum, int n){
  int i = blockIdx.x*blockDim.x + threadIdx.x;
  if (i == 0) rowptr[0] = 0;
  if (i < n) rowptr[i + 1] += bsum[i >> 10];
}

__global__ void k_scatter(const int* __restrict__ ei, int E, int Nn, const int* __restrict__ rowptr,
                          int* __restrict__ cursor, int* __restrict__ srcs){
  int total = E + Nn;
  for (int e = blockIdx.x*blockDim.x + threadIdx.x; e < total; e += gridDim.x*blockDim.x){
    int s, d;
    if (e < E){ s = ei[e]; d = ei[E + e]; } else { s = d = e - E; }
    int pos = rowptr[d] + atomicAdd(&cursor[d], 1);
    srcs[pos] = s;
  }
}

__global__ void k_transpose_w(const float* __restrict__ W, unsigned short* __restrict__ Wt){
  int t = blockIdx.x*blockDim.x + threadIdx.x; // 65536 threads
  int k = t >> 8, c = t & 255;
  Wt[c*256 + k] = f2bf(W[k*256 + c]);
}

// ---------------- GEMM with LDS-staged A + attention-logit epilogue ----------------
// block: 512 threads = 8 waves, 64 rows x 256 cols. wave = (rh, head): rh=wid>>2, head=wid&3.
// A staged coalesced into padded LDS; B (Wt) from global (L2-resident 128KB).
template<bool AF32>
__global__ __launch_bounds__(512) void k_gemm2(const void* __restrict__ Av,
                                               const unsigned short* __restrict__ Wt,
                                               const float* __restrict__ asrc,
                                               const float* __restrict__ adst,
                                               unsigned short* __restrict__ H,
                                               float* __restrict__ als,
                                               float* __restrict__ ald,
                                               int Nn){
  __shared__ unsigned short As[64][264];   // +8 pad: row stride 528B spreads banks
  int tid = threadIdx.x;
  int wid = tid >> 6, lane = tid & 63;
  int w = wid & 3, rh = wid >> 2;
  int row0 = blockIdx.x * 64;

  const unsigned short* a16 = (const unsigned short*)Av;
  const float*          a32 = (const float*)Av;

  // stage A: 64 rows x 256 bf16. 2048 chunks of 16B; thread t does 4.
  #pragma unroll
  for (int it = 0; it < 4; ++it){
    int li = it*512 + tid;
    int rr = li >> 5, c16 = li & 31;
    int gr = row0 + rr; if (gr >= Nn) gr = Nn - 1;
    if (AF32){
      const float* ap = a32 + (size_t)gr*256 + c16*8;
      float4 v0 = *reinterpret_cast<const float4*>(ap);
      float4 v1 = *reinterpret_cast<const float4*>(ap + 4);
      union { uint4 q; unsigned short s[8]; } u;
      u.s[0]=f2bf(v0.x); u.s[1]=f2bf(v0.y); u.s[2]=f2bf(v0.z); u.s[3]=f2bf(v0.w);
      u.s[4]=f2bf(v1.x); u.s[5]=f2bf(v1.y); u.s[6]=f2bf(v1.z); u.s[7]=f2bf(v1.w);
      *reinterpret_cast<uint4*>(&As[rr][c16*8]) = u.q;
    } else {
      uint4 v = *reinterpret_cast<const uint4*>(a16 + (size_t)gr*256 + c16*8);
      *reinterpret_cast<uint4*>(&As[rr][c16*8]) = v;
    }
  }
  __syncthreads();

  int r = lane & 15, kg = lane >> 4;
  f32x4 acc[2][4] = {};

  #pragma unroll
  for (int k0 = 0; k0 < 256; k0 += 32){
    bf16x8 a0 = *reinterpret_cast<const bf16x8*>(&As[rh*32 +      r][kg*8 + k0]);
    bf16x8 a1 = *reinterpret_cast<const bf16x8*>(&As[rh*32 + 16 + r][kg*8 + k0]);
    #pragma unroll
    for (int c = 0; c < 4; ++c){
      bf16x8 bfr = *reinterpret_cast<const bf16x8*>(Wt + (size_t)(w*64 + c*16 + r)*256 + kg*8 + k0);
      acc[0][c] = __builtin_amdgcn_mfma_f32_16x16x32_bf16(a0, bfr, acc[0][c], 0, 0, 0);
      acc[1][c] = __builtin_amdgcn_mfma_f32_16x16x32_bf16(a1, bfr, acc[1][c], 0, 0, 0);
    }
  }

  int rbase = row0 + rh*32;
  // store H (bf16). C layout: col = c*16 + r, row(within tile) = kg*4 + i.
  #pragma unroll
  for (int n = 0; n < 2; ++n){
    #pragma unroll
    for (int i = 0; i < 4; ++i){
      int row = rbase + n*16 + kg*4 + i;
      if (row < Nn){
        #pragma unroll
        for (int c = 0; c < 4; ++c)
          H[(size_t)row*256 + w*64 + c*16 + r] = f2bf(acc[n][c][i]);
      }
    }
  }

  // fused attention logits
  float as_c[4], ad_c[4];
  #pragma unroll
  for (int c = 0; c < 4; ++c){
    as_c[c] = asrc[w*64 + c*16 + r];
    ad_c[c] = adst[w*64 + c*16 + r];
  }
  #pragma unroll
  for (int n = 0; n < 2; ++n){
    #pragma unroll
    for (int i = 0; i < 4; ++i){
      float ps = acc[n][0][i]*as_c[0] + acc[n][1][i]*as_c[1]
               + acc[n][2][i]*as_c[2] + acc[n][3][i]*as_c[3];
      float pd = acc[n][0][i]*ad_c[0] + acc[n][1][i]*ad_c[1]
               + acc[n][2][i]*ad_c[2] + acc[n][3][i]*ad_c[3];
      #pragma unroll
      for (int off = 1; off < 16; off <<= 1){
        ps += __shfl_xor(ps, off, 64);
        pd += __shfl_xor(pd, off, 64);
      }
      int row = rbase + n*16 + kg*4 + i;
      if (r == 0 && row < Nn){
        als[row*4 + w] = ps;
        ald[row*4 + w] = pd;
      }
    }
  }
}

// ---------------- fused softmax + weighted gather: one wave per destination node ----------------
// w_e = exp(leaky_relu(als[src]+ald[dst])) computed inline (no max subtraction needed:
// logits bounded well within f32 exp range; softmax is shift-invariant so result identical).
// Denominator accumulated in-register. 2 edges per load instr, unroll x4 = 8 edges in flight.
// MODE 0: concat heads, +bias, ELU -> bf16 [N,256].  MODE 1: head-mean, +bias, log_softmax -> f32 [N,64].
template<int MODE>
__global__ void k_gather3(const unsigned short* __restrict__ Hm, const int* __restrict__ rowptr,
                          const int* __restrict__ srcs, const float* __restrict__ als,
                          const float* __restrict__ ald, const float* __restrict__ bias,
                          unsigned short* __restrict__ actout, float* __restrict__ finalout, int Nn){
  int gid = blockIdx.x*blockDim.x + threadIdx.x;
  int node = gid >> 6, lane = gid & 63;
  if (node >= Nn) return;
  int half = lane >> 5;          // which edge of the pair
  int l32  = lane & 31;
  int fbase = l32 * 8;           // features fbase..fbase+7
  int hd = l32 >> 3;             // head of those features
  unsigned voff_feat = (unsigned)(l32 * 16);   // bytes into the 512B H row

  int beg = rowptr[node], deg = rowptr[node + 1] - beg;
  float4 adv = *reinterpret_cast<const float4*>(ald + (size_t)node*4);
  float aldh = (hd == 0) ? adv.x : (hd == 1) ? adv.y : (hd == 2) ? adv.z : adv.w;

  float acc[4][8];
  #pragma unroll
  for (int u = 0; u < 4; ++u)
    #pragma unroll
    for (int i = 0; i < 8; ++i) acc[u][i] = 0.f;
  float sw = 0.f;

  const char* Hb = (const char*)Hm;
  const char* Ab = (const char*)als;

  for (int cb = 0; cb < deg; cb += 64){
    int chunk = min(64, deg - cb);
    int mysrc = (cb + lane < deg) ? srcs[beg + cb + lane] : 0;
    int jmax8 = chunk & ~7;
    int j = 0;
    for (; j < jmax8; j += 8){
      #pragma unroll
      for (int u = 0; u < 4; ++u){
        int e0 = j + 2*u;
        int sA = __builtin_amdgcn_readlane(mysrc, e0);
        int sB = __builtin_amdgcn_readlane(mysrc, e0 + 1);
        int sM = half ? sB : sA;
        uint4 hw = *reinterpret_cast<const uint4*>(Hb + (unsigned)sM*512u + voff_feat);
        float av = *reinterpret_cast<const float*>(Ab + ((unsigned)sM << 4) + ((unsigned)hd << 2));
        float l = av + aldh; l = l > 0.f ? l : 0.2f*l;
        float wgt = __expf(l);
        sw += wgt;
        float h0 = __uint_as_float(hw.x << 16);
        float h1 = __uint_as_float(hw.x & 0xffff0000u);
        float h2 = __uint_as_float(hw.y << 16);
        float h3 = __uint_as_float(hw.y & 0xffff0000u);
        float h4 = __uint_as_float(hw.z << 16);
        float h5 = __uint_as_float(hw.z & 0xffff0000u);
        float h6 = __uint_as_float(hw.w << 16);
        float h7 = __uint_as_float(hw.w & 0xffff0000u);
        acc[u][0] = fmaf(wgt, h0, acc[u][0]);
        acc[u][1] = fmaf(wgt, h1, acc[u][1]);
        acc[u][2] = fmaf(wgt, h2, acc[u][2]);
        acc[u][3] = fmaf(wgt, h3, acc[u][3]);
        acc[u][4] = fmaf(wgt, h4, acc[u][4]);
        acc[u][5] = fmaf(wgt, h5, acc[u][5]);
        acc[u][6] = fmaf(wgt, h6, acc[u][6]);
        acc[u][7] = fmaf(wgt, h7, acc[u][7]);
      }
    }
    for (; j < chunk; j += 2){
      int eA = j;
      int eB = (j + 1 < chunk) ? (j + 1) : j;
      int sA = __builtin_amdgcn_readlane(mysrc, eA);
      int sB = __builtin_amdgcn_readlane(mysrc, eB);
      int sM = half ? sB : sA;
      uint4 hw = *reinterpret_cast<const uint4*>(Hb + (unsigned)sM*512u + voff_feat);
      float av = *reinterpret_cast<const float*>(Ab + ((unsigned)sM << 4) + ((unsigned)hd << 2));
      float l = av + aldh; l = l > 0.f ? l : 0.2f*l;
      float wgt = __expf(l);
      if (j + half >= chunk) wgt = 0.f;
      sw += wgt;
      float h0 = __uint_as_float(hw.x << 16);
      float h1 = __uint_as_float(hw.x & 0xffff0000u);
      float h2 = __uint_as_float(hw.y << 16);
      float h3 = __uint_as_float(hw.y & 0xffff0000u);
      float h4 = __uint_as_float(hw.z << 16);
      float h5 = __uint_as_float(hw.z & 0xffff0000u);
      float h6 = __uint_as_float(hw.w << 16);
      float h7 = __uint_as_float(hw.w & 0xffff0000u);
      acc[0][0] = fmaf(wgt, h0, acc[0][0]);
      acc[0][1] = fmaf(wgt, h1, acc[0][1]);
      acc[0][2] = fmaf(wgt, h2, acc[0][2]);
      acc[0][3] = fmaf(wgt, h3, acc[0][3]);
      acc[0][4] = fmaf(wgt, h4, acc[0][4]);
      acc[0][5] = fmaf(wgt, h5, acc[0][5]);
      acc[0][6] = fmaf(wgt, h6, acc[0][6]);
      acc[0][7] = fmaf(wgt, h7, acc[0][7]);
    }
  }

  // fold 4 sets + the two halves; denominator likewise
  float accf[8];
  #pragma unroll
  for (int i = 0; i < 8; ++i){
    float t = acc[0][i] + acc[1][i] + acc[2][i] + acc[3][i];
    t += __shfl_xor(t, 32, 64);
    accf[i] = t;
  }
  float s = sw + __shfl_xor(sw, 32, 64);
  float inv = 1.f / s;

  if (MODE == 0){
    if (lane < 32){
      float4 b0 = *reinterpret_cast<const float4*>(bias + fbase);
      float4 b1 = *reinterpret_cast<const float4*>(bias + fbase + 4);
      float o[8];
      o[0] = accf[0]*inv + b0.x; o[1] = accf[1]*inv + b0.y;
      o[2] = accf[2]*inv + b0.z; o[3] = accf[3]*inv + b0.w;
      o[4] = accf[4]*inv + b1.x; o[5] = accf[5]*inv + b1.y;
      o[6] = accf[6]*inv + b1.z; o[7] = accf[7]*inv + b1.w;
      u16x8 pk;
      #pragma unroll
      for (int i = 0; i < 8; ++i){
        float v = o[i];
        v = v > 0.f ? v : __expf(v) - 1.f;
        pk[i] = f2bf(v);
      }
      *reinterpret_cast<u16x8*>(actout + (size_t)node*256 + fbase) = pk;
    }
  } else {
    float v[8];
    #pragma unroll
    for (int i = 0; i < 8; ++i){
      float t = accf[i]*inv;
      t += __shfl_xor(t, 8, 64);
      t += __shfl_xor(t, 16, 64);
      v[i] = t;
    }
    int k = l32 & 7;               // dim block 0..7 (dims k*8..k*8+7)
    float4 b0 = *reinterpret_cast<const float4*>(bias + k*8);
    float4 b1 = *reinterpret_cast<const float4*>(bias + k*8 + 4);
    v[0] = v[0]*0.25f + b0.x; v[1] = v[1]*0.25f + b0.y;
    v[2] = v[2]*0.25f + b0.z; v[3] = v[3]*0.25f + b0.w;
    v[4] = v[4]*0.25f + b1.x; v[5] = v[5]*0.25f + b1.y;
    v[6] = v[6]*0.25f + b1.z; v[7] = v[7]*0.25f + b1.w;
    float mx = v[0];
    #pragma unroll
    for (int i = 1; i < 8; ++i) mx = fmaxf(mx, v[i]);
    #pragma unroll
    for (int off = 1; off < 8; off <<= 1) mx = fmaxf(mx, __shfl_xor(mx, off, 64));
    float se = 0.f;
    #pragma unroll
    for (int i = 0; i < 8; ++i) se += __expf(v[i] - mx);
    #pragma unroll
    for (int off = 1; off < 8; off <<= 1) se += __shfl_xor(se, off, 64);
    float lse = mx + __logf(se);
    if (lane < 8){
      float4 o0, o1;
      o0.x = v[0]-lse; o0.y = v[1]-lse; o0.z = v[2]-lse; o0.w = v[3]-lse;
      o1.x = v[4]-lse; o1.y = v[5]-lse; o1.z = v[6]-lse; o1.w = v[7]-lse;
      float* dst = finalout + (size_t)node*64 + lane*8;
      *reinterpret_cast<float4*>(dst)     = o0;
      *reinterpret_cast<float4*>(dst + 4) = o1;
    }
  }
}

extern "C" void kernel_launch(void* const* d_in, const int* in_sizes, int n_in,
                              void* d_out, int out_size, void* d_ws, size_t ws_size,
                              hipStream_t stream){
  const float* x     = (const float*)d_in[0];
  const int*   ei    = (const int*)  d_in[1];
  const float* W1    = (const float*)d_in[2];
  const float* asrc1 = (const float*)d_in[3];
  const float* adst1 = (const float*)d_in[4];
  const float* b1    = (const float*)d_in[5];
  const float* W2    = (const float*)d_in[6];
  const float* asrc2 = (const float*)d_in[7];
  const float* adst2 = (const float*)d_in[8];
  const float* b2    = (const float*)d_in[9];
  const float* W3    = (const float*)d_in[10];
  const float* asrc3 = (const float*)d_in[11];
  const float* adst3 = (const float*)d_in[12];
  const float* b3    = (const float*)d_in[13];
  float* out = (float*)d_out;

  int N = in_sizes[0] / 256;
  int E = in_sizes[1] / 2;

  char* p = (char*)d_ws;
  auto carve = [&](size_t bytes){ void* r = (void*)p; p += (bytes + 511) & ~(size_t)511; return r; };
  unsigned short* bufA = (unsigned short*)carve((size_t)N*256*2);
  unsigned short* bufH = (unsigned short*)carve((size_t)N*256*2);
  unsigned short* bufB = (unsigned short*)carve((size_t)N*256*2);
  unsigned short* wt1  = (unsigned short*)carve(256*256*2);
  unsigned short* wt2  = (unsigned short*)carve(256*256*2);
  unsigned short* wt3  = (unsigned short*)carve(256*256*2);
  float* als   = (float*)carve((size_t)N*4*4);
  float* ald   = (float*)carve((size_t)N*4*4);
  int* rowptr  = (int*)carve((size_t)(N+1)*4);
  int* cursor  = (int*)carve((size_t)N*4);
  int* bsum    = (int*)carve((size_t)1024*4);
  int* srcs    = (int*)carve((size_t)(E+N)*4);

  // CSR build
  hipMemsetAsync(cursor, 0, (size_t)N*4, stream);
  k_hist<<<2048, 256, 0, stream>>>(ei, E, N, cursor);
  int nb = (N + 1023) / 1024;
  k_scan1<<<nb, 1024, 0, stream>>>(cursor, rowptr, bsum, N);
  k_scan2<<<1, 1024, 0, stream>>>(bsum, nb);
  k_scan3<<<(N + 255)/256, 256, 0, stream>>>(rowptr, bsum, N);
  hipMemsetAsync(cursor, 0, (size_t)N*4, stream);
  k_scatter<<<2048, 256, 0, stream>>>(ei, E, N, rowptr, cursor, srcs);

  // weight transposes (tiny)
  k_transpose_w<<<256, 256, 0, stream>>>(W1, wt1);
  k_transpose_w<<<256, 256, 0, stream>>>(W2, wt2);
  k_transpose_w<<<256, 256, 0, stream>>>(W3, wt3);

  int gemm_grid  = (N + 63) / 64;
  int nodeblocks = (N*64 + 255)/256;

  // layer 1 (A = x in f32, converted during LDS staging)
  k_gemm2<true><<<gemm_grid, 512, 0, stream>>>(x, wt1, asrc1, adst1, bufH, als, ald, N);
  k_gather3<0><<<nodeblocks, 256, 0, stream>>>(bufH, rowptr, srcs, als, ald, b1, bufB, nullptr, N);
  // layer 2
  k_gemm2<false><<<gemm_grid, 512, 0, stream>>>(bufB, wt2, asrc2, adst2, bufH, als, ald, N);
  k_gather3<0><<<nodeblocks, 256, 0, stream>>>(bufH, rowptr, srcs, als, ald, b2, bufA, nullptr, N);
  // layer 3
  k_gemm2<false><<<gemm_grid, 512, 0, stream>>>(bufA, wt3, asrc3, adst3, bufH, als, ald, N);
  k_gather3<1><<<nodeblocks, 256, 0, stream>>>(bufH, rowptr, srcs, als, ald, b3, nullptr, out, N);
}

// Round 5
// 418.030 us; speedup vs baseline: 1.6815x; 1.0176x over previous
//
#include <hip/hip_runtime.h>
#include <stdint.h>

typedef __bf16 bf16x8 __attribute__((ext_vector_type(8)));
typedef float f32x4 __attribute__((ext_vector_type(4)));
typedef unsigned short u16x8 __attribute__((ext_vector_type(8)));

__device__ __forceinline__ unsigned short f2bf(float f){
  union { float f; unsigned u; } c; c.f = f;
  unsigned u = c.u;
  unsigned r = u + 0x7FFFu + ((u >> 16) & 1u);
  return (unsigned short)(r >> 16);
}

// ---------------- CSR build (group edges by dst) ----------------
__global__ void k_hist(const int* __restrict__ ei, int E, int Nn, int* __restrict__ counts){
  int total = E + Nn;
  for (int e = blockIdx.x*blockDim.x + threadIdx.x; e < total; e += gridDim.x*blockDim.x){
    int d = (e < E) ? ei[E + e] : (e - E);
    atomicAdd(&counts[d], 1);
  }
}

__global__ __launch_bounds__(1024) void k_scan1(const int* __restrict__ counts, int* __restrict__ rowptr,
                                                int* __restrict__ bsum, int n){
  __shared__ int wsum[17];
  int tid = threadIdx.x, lane = tid & 63, wid = tid >> 6;
  int i = blockIdx.x*1024 + tid;
  int v = (i < n) ? counts[i] : 0;
  int iv = v;
  #pragma unroll
  for (int off = 1; off < 64; off <<= 1){
    int t = __shfl_up(iv, off, 64);
    if (lane >= off) iv += t;
  }
  if (lane == 63) wsum[wid] = iv;
  __syncthreads();
  if (tid == 0){
    int run = 0;
    for (int w = 0; w < 16; ++w){ int t = wsum[w]; wsum[w] = run; run += t; }
    wsum[16] = run;
  }
  __syncthreads();
  if (i < n) rowptr[i + 1] = iv + wsum[wid];
  if (tid == 0) bsum[blockIdx.x] = wsum[16];
}

__global__ __launch_bounds__(1024) void k_scan2(int* __restrict__ bsum, int nb){
  __shared__ int wsum[17];
  int tid = threadIdx.x, lane = tid & 63, wid = tid >> 6;
  int v = (tid < nb) ? bsum[tid] : 0;
  int iv = v;
  #pragma unroll
  for (int off = 1; off < 64; off <<= 1){
    int t = __shfl_up(iv, off, 64);
    if (lane >= off) iv += t;
  }
  if (lane == 63) wsum[wid] = iv;
  __syncthreads();
  if (tid == 0){
    int run = 0;
    for (int w = 0; w < 16; ++w){ int t = wsum[w]; wsum[w] = run; run += t; }
  }
  __syncthreads();
  if (tid < nb) bsum[tid] = iv + wsum[wid] - v;   // exclusive
}

// finalize rowptr and seed cursor[i] = rowptr[i] (segment start) in the same pass
__global__ void k_scan3(int* __restrict__ rowptr, const int* __restrict__ bsum,
                        const int* __restrict__ counts, int* __restrict__ cursor, int n){
  int i = blockIdx.x*blockDim.x + threadIdx.x;
  if (i == 0) rowptr[0] = 0;
  if (i < n){
    int v = rowptr[i + 1] + bsum[i >> 10];
    rowptr[i + 1] = v;
    cursor[i] = v - counts[i];
  }
}

__global__ void k_scatter(const int* __restrict__ ei, int E, int Nn,
                          int* __restrict__ cursor, int* __restrict__ srcs){
  int total = E + Nn;
  for (int e = blockIdx.x*blockDim.x + threadIdx.x; e < total; e += gridDim.x*blockDim.x){
    int s, d;
    if (e < E){ s = ei[e]; d = ei[E + e]; } else { s = d = e - E; }
    int pos = atomicAdd(&cursor[d], 1);
    srcs[pos] = s;
  }
}

// all three weight transposes in one launch: t in [0, 3*65536)
__global__ void k_transpose_all(const float* __restrict__ W1, const float* __restrict__ W2,
                                const float* __restrict__ W3, unsigned short* __restrict__ wt1,
                                unsigned short* __restrict__ wt2, unsigned short* __restrict__ wt3){
  int t = blockIdx.x*blockDim.x + threadIdx.x;
  int which = t >> 16, li = t & 65535;
  int k = li >> 8, c = li & 255;
  const float* W = (which == 0) ? W1 : (which == 1) ? W2 : W3;
  unsigned short* Wt = (which == 0) ? wt1 : (which == 1) ? wt2 : wt3;
  Wt[c*256 + k] = f2bf(W[k*256 + c]);
}

// ---------------- pipelined GEMM (2 tiles/block) + attention-logit epilogue ----------------
// 512 threads = 8 waves; tile = 64 rows x 256 cols. wave = (rh, head).
// A-tile prefetched to regs for tile t+G while tile t computes; B (Wt) stays L2-hot.
template<bool AF32>
__global__ __launch_bounds__(512) void k_gemm3(const void* __restrict__ Av,
                                               const unsigned short* __restrict__ Wt,
                                               const float* __restrict__ asrc,
                                               const float* __restrict__ adst,
                                               unsigned short* __restrict__ H,
                                               float* __restrict__ als,
                                               float* __restrict__ ald,
                                               int Nn, int T, int G){
  __shared__ unsigned short As[64][264];   // pad keeps 8-consecutive-lane groups conflict-free
  int tid = threadIdx.x;
  int wid = tid >> 6, lane = tid & 63;
  int w = wid & 3, rh = wid >> 2;
  int r = lane & 15, kg = lane >> 4;

  const unsigned short* a16 = (const unsigned short*)Av;
  const float*          a32 = (const float*)Av;

  uint4  sreg[4];
  float4 sregf[4][2];

  auto load_tile = [&](int t){
    #pragma unroll
    for (int it = 0; it < 4; ++it){
      int li = it*512 + tid;
      int rr = li >> 5, c16 = li & 31;
      int gr = t*64 + rr; if (gr >= Nn) gr = Nn - 1;
      if (AF32){
        const float* ap = a32 + (size_t)gr*256 + c16*8;
        sregf[it][0] = *reinterpret_cast<const float4*>(ap);
        sregf[it][1] = *reinterpret_cast<const float4*>(ap + 4);
      } else {
        sreg[it] = *reinterpret_cast<const uint4*>(a16 + (size_t)gr*256 + c16*8);
      }
    }
  };
  auto write_lds = [&](){
    #pragma unroll
    for (int it = 0; it < 4; ++it){
      int li = it*512 + tid;
      int rr = li >> 5, c16 = li & 31;
      if (AF32){
        float4 v0 = sregf[it][0], v1 = sregf[it][1];
        union { uint4 q; unsigned short s[8]; } u;
        u.s[0]=f2bf(v0.x); u.s[1]=f2bf(v0.y); u.s[2]=f2bf(v0.z); u.s[3]=f2bf(v0.w);
        u.s[4]=f2bf(v1.x); u.s[5]=f2bf(v1.y); u.s[6]=f2bf(v1.z); u.s[7]=f2bf(v1.w);
        *reinterpret_cast<uint4*>(&As[rr][c16*8]) = u.q;
      } else {
        *reinterpret_cast<uint4*>(&As[rr][c16*8]) = sreg[it];
      }
    }
  };

  float as_c[4], ad_c[4];
  #pragma unroll
  for (int c = 0; c < 4; ++c){
    as_c[c] = asrc[w*64 + c*16 + r];
    ad_c[c] = adst[w*64 + c*16 + r];
  }

  int t = blockIdx.x;
  if (t >= T) return;
  load_tile(t);

  for (;;){
    write_lds();
    __syncthreads();
    int tn = t + G;
    bool more = (tn < T);
    if (more) load_tile(tn);          // prefetch next tile while computing this one

    f32x4 acc[2][4] = {};
    #pragma unroll
    for (int k0 = 0; k0 < 256; k0 += 32){
      bf16x8 a0 = *reinterpret_cast<const bf16x8*>(&As[rh*32 +      r][kg*8 + k0]);
      bf16x8 a1 = *reinterpret_cast<const bf16x8*>(&As[rh*32 + 16 + r][kg*8 + k0]);
      #pragma unroll
      for (int c = 0; c < 4; ++c){
        bf16x8 bfr = *reinterpret_cast<const bf16x8*>(Wt + (size_t)(w*64 + c*16 + r)*256 + kg*8 + k0);
        acc[0][c] = __builtin_amdgcn_mfma_f32_16x16x32_bf16(a0, bfr, acc[0][c], 0, 0, 0);
        acc[1][c] = __builtin_amdgcn_mfma_f32_16x16x32_bf16(a1, bfr, acc[1][c], 0, 0, 0);
      }
    }

    int rbase = t*64 + rh*32;
    #pragma unroll
    for (int n = 0; n < 2; ++n){
      #pragma unroll
      for (int i = 0; i < 4; ++i){
        int row = rbase + n*16 + kg*4 + i;
        if (row < Nn){
          #pragma unroll
          for (int c = 0; c < 4; ++c)
            H[(size_t)row*256 + w*64 + c*16 + r] = f2bf(acc[n][c][i]);
        }
      }
    }
    #pragma unroll
    for (int n = 0; n < 2; ++n){
      #pragma unroll
      for (int i = 0; i < 4; ++i){
        float ps = acc[n][0][i]*as_c[0] + acc[n][1][i]*as_c[1]
                 + acc[n][2][i]*as_c[2] + acc[n][3][i]*as_c[3];
        float pd = acc[n][0][i]*ad_c[0] + acc[n][1][i]*ad_c[1]
                 + acc[n][2][i]*ad_c[2] + acc[n][3][i]*ad_c[3];
        #pragma unroll
        for (int off = 1; off < 16; off <<= 1){
          ps += __shfl_xor(ps, off, 64);
          pd += __shfl_xor(pd, off, 64);
        }
        int row = rbase + n*16 + kg*4 + i;
        if (r == 0 && row < Nn){
          als[row*4 + w] = ps;
          ald[row*4 + w] = pd;
        }
      }
    }

    if (!more) break;
    __syncthreads();                  // LDS safe to overwrite
    t = tn;
  }
}

// ---------------- fused softmax + weighted gather, LDS weight table ----------------
// Per 64-edge chunk: each lane computes its OWN edge's 4-head exp-weights once
// (coalesced als float4 gather), stores them in a per-wave LDS table, and keeps
// per-lane float4 denominator partials. Inner loop per edge-pair: bperm src,
// 512B row load, 4B LDS weight read, unpack+FMA. No max-subtraction needed
// (logits bounded; softmax shift-invariant).
template<int MODE>
__global__ __launch_bounds__(256) void k_gather4(const unsigned short* __restrict__ Hm,
                          const int* __restrict__ rowptr, const int* __restrict__ srcs,
                          const float* __restrict__ als, const float* __restrict__ ald,
                          const float* __restrict__ bias,
                          unsigned short* __restrict__ actout, float* __restrict__ finalout, int Nn){
  __shared__ float wlds[4][64][4];
  int gid = blockIdx.x*blockDim.x + threadIdx.x;
  int node = gid >> 6, lane = gid & 63;
  if (node >= Nn) return;
  int wv_id = threadIdx.x >> 6;
  int half = lane >> 5;
  int l32  = lane & 31;
  int fbase = l32 * 8;
  int hd = l32 >> 3;
  unsigned voff = (unsigned)(l32 * 16);

  int beg = rowptr[node], deg = rowptr[node + 1] - beg;
  float4 adv = *reinterpret_cast<const float4*>(ald + (size_t)node*4);

  float acc[4][8];
  #pragma unroll
  for (int u = 0; u < 4; ++u)
    #pragma unroll
    for (int i = 0; i < 8; ++i) acc[u][i] = 0.f;
  float sw0 = 0.f, sw1 = 0.f, sw2 = 0.f, sw3 = 0.f;

  const char* Hb = (const char*)Hm;
  const float* wrow = &wlds[wv_id][0][0];

  for (int cb = 0; cb < deg; cb += 64){
    int chunk = min(64, deg - cb);
    bool valid = (lane < chunk);
    int mysrc = valid ? srcs[beg + cb + lane] : 0;

    // per-lane weights for edge (cb+lane), all 4 heads
    float4 a = *reinterpret_cast<const float4*>(als + (size_t)mysrc*4);
    float l0 = a.x + adv.x; l0 = l0 > 0.f ? l0 : 0.2f*l0;
    float l1 = a.y + adv.y; l1 = l1 > 0.f ? l1 : 0.2f*l1;
    float l2 = a.z + adv.z; l2 = l2 > 0.f ? l2 : 0.2f*l2;
    float l3 = a.w + adv.w; l3 = l3 > 0.f ? l3 : 0.2f*l3;
    float4 wvv;
    wvv.x = valid ? __expf(l0) : 0.f;
    wvv.y = valid ? __expf(l1) : 0.f;
    wvv.z = valid ? __expf(l2) : 0.f;
    wvv.w = valid ? __expf(l3) : 0.f;
    sw0 += wvv.x; sw1 += wvv.y; sw2 += wvv.z; sw3 += wvv.w;
    *reinterpret_cast<float4*>(&wlds[wv_id][lane][0]) = wvv;
    asm volatile("s_waitcnt lgkmcnt(0)" ::: "memory");
    __builtin_amdgcn_sched_barrier(0);

    // pairs (e, e+1): half 0 -> e, half 1 -> e+1. OOB slots have weight 0, src 0.
    for (int e = 0; e < chunk; e += 8){
      #pragma unroll
      for (int u = 0; u < 4; ++u){
        int pe = e + 2*u;
        int sM = __shfl(mysrc, pe + half, 64);
        uint4 hw = *reinterpret_cast<const uint4*>(Hb + (unsigned)sM*512u + voff);
        float wgt = wrow[(unsigned)(pe + half)*4u + (unsigned)hd];
        float h0 = __uint_as_float(hw.x << 16);
        float h1 = __uint_as_float(hw.x & 0xffff0000u);
        float h2 = __uint_as_float(hw.y << 16);
        float h3 = __uint_as_float(hw.y & 0xffff0000u);
        float h4 = __uint_as_float(hw.z << 16);
        float h5 = __uint_as_float(hw.z & 0xffff0000u);
        float h6 = __uint_as_float(hw.w << 16);
        float h7 = __uint_as_float(hw.w & 0xffff0000u);
        acc[u][0] = fmaf(wgt, h0, acc[u][0]);
        acc[u][1] = fmaf(wgt, h1, acc[u][1]);
        acc[u][2] = fmaf(wgt, h2, acc[u][2]);
        acc[u][3] = fmaf(wgt, h3, acc[u][3]);
        acc[u][4] = fmaf(wgt, h4, acc[u][4]);
        acc[u][5] = fmaf(wgt, h5, acc[u][5]);
        acc[u][6] = fmaf(wgt, h6, acc[u][6]);
        acc[u][7] = fmaf(wgt, h7, acc[u][7]);
      }
    }
  }

  // reduce denominators across the wave (per-lane partials cover distinct edges)
  #pragma unroll
  for (int off = 1; off < 64; off <<= 1){
    sw0 += __shfl_xor(sw0, off, 64);
    sw1 += __shfl_xor(sw1, off, 64);
    sw2 += __shfl_xor(sw2, off, 64);
    sw3 += __shfl_xor(sw3, off, 64);
  }
  float sden = (hd == 0) ? sw0 : (hd == 1) ? sw1 : (hd == 2) ? sw2 : sw3;
  float inv = 1.f / sden;

  float accf[8];
  #pragma unroll
  for (int i = 0; i < 8; ++i){
    float t = acc[0][i] + acc[1][i] + acc[2][i] + acc[3][i];
    t += __shfl_xor(t, 32, 64);
    accf[i] = t;
  }

  if (MODE == 0){
    if (lane < 32){
      float4 b0 = *reinterpret_cast<const float4*>(bias + fbase);
      float4 b1 = *reinterpret_cast<const float4*>(bias + fbase + 4);
      float o[8];
      o[0] = accf[0]*inv + b0.x; o[1] = accf[1]*inv + b0.y;
      o[2] = accf[2]*inv + b0.z; o[3] = accf[3]*inv + b0.w;
      o[4] = accf[4]*inv + b1.x; o[5] = accf[5]*inv + b1.y;
      o[6] = accf[6]*inv + b1.z; o[7] = accf[7]*inv + b1.w;
      u16x8 pk;
      #pragma unroll
      for (int i = 0; i < 8; ++i){
        float v = o[i];
        v = v > 0.f ? v : __expf(v) - 1.f;
        pk[i] = f2bf(v);
      }
      *reinterpret_cast<u16x8*>(actout + (size_t)node*256 + fbase) = pk;
    }
  } else {
    float v[8];
    #pragma unroll
    for (int i = 0; i < 8; ++i){
      float t = accf[i]*inv;
      t += __shfl_xor(t, 8, 64);
      t += __shfl_xor(t, 16, 64);
      v[i] = t;
    }
    int k = l32 & 7;
    float4 b0 = *reinterpret_cast<const float4*>(bias + k*8);
    float4 b1 = *reinterpret_cast<const float4*>(bias + k*8 + 4);
    v[0] = v[0]*0.25f + b0.x; v[1] = v[1]*0.25f + b0.y;
    v[2] = v[2]*0.25f + b0.z; v[3] = v[3]*0.25f + b0.w;
    v[4] = v[4]*0.25f + b1.x; v[5] = v[5]*0.25f + b1.y;
    v[6] = v[6]*0.25f + b1.z; v[7] = v[7]*0.25f + b1.w;
    float mx = v[0];
    #pragma unroll
    for (int i = 1; i < 8; ++i) mx = fmaxf(mx, v[i]);
    #pragma unroll
    for (int off = 1; off < 8; off <<= 1) mx = fmaxf(mx, __shfl_xor(mx, off, 64));
    float se = 0.f;
    #pragma unroll
    for (int i = 0; i < 8; ++i) se += __expf(v[i] - mx);
    #pragma unroll
    for (int off = 1; off < 8; off <<= 1) se += __shfl_xor(se, off, 64);
    float lse = mx + __logf(se);
    if (lane < 8){
      float4 o0, o1;
      o0.x = v[0]-lse; o0.y = v[1]-lse; o0.z = v[2]-lse; o0.w = v[3]-lse;
      o1.x = v[4]-lse; o1.y = v[5]-lse; o1.z = v[6]-lse; o1.w = v[7]-lse;
      float* dst = finalout + (size_t)node*64 + lane*8;
      *reinterpret_cast<float4*>(dst)     = o0;
      *reinterpret_cast<float4*>(dst + 4) = o1;
    }
  }
}

extern "C" void kernel_launch(void* const* d_in, const int* in_sizes, int n_in,
                              void* d_out, int out_size, void* d_ws, size_t ws_size,
                              hipStream_t stream){
  const float* x     = (const float*)d_in[0];
  const int*   ei    = (const int*)  d_in[1];
  const float* W1    = (const float*)d_in[2];
  const float* asrc1 = (const float*)d_in[3];
  const float* adst1 = (const float*)d_in[4];
  const float* b1    = (const float*)d_in[5];
  const float* W2    = (const float*)d_in[6];
  const float* asrc2 = (const float*)d_in[7];
  const float* adst2 = (const float*)d_in[8];
  const float* b2    = (const float*)d_in[9];
  const float* W3    = (const float*)d_in[10];
  const float* asrc3 = (const float*)d_in[11];
  const float* adst3 = (const float*)d_in[12];
  const float* b3    = (const float*)d_in[13];
  float* out = (float*)d_out;

  int N = in_sizes[0] / 256;
  int E = in_sizes[1] / 2;

  char* p = (char*)d_ws;
  auto carve = [&](size_t bytes){ void* r = (void*)p; p += (bytes + 511) & ~(size_t)511; return r; };
  unsigned short* bufA = (unsigned short*)carve((size_t)N*256*2);
  unsigned short* bufH = (unsigned short*)carve((size_t)N*256*2);
  unsigned short* bufB = (unsigned short*)carve((size_t)N*256*2);
  unsigned short* wt1  = (unsigned short*)carve(256*256*2);
  unsigned short* wt2  = (unsigned short*)carve(256*256*2);
  unsigned short* wt3  = (unsigned short*)carve(256*256*2);
  float* als    = (float*)carve((size_t)N*4*4);
  float* ald    = (float*)carve((size_t)N*4*4);
  int* rowptr   = (int*)carve((size_t)(N+1)*4);
  int* counts   = (int*)carve((size_t)N*4);
  int* cursor   = (int*)carve((size_t)N*4);
  int* bsum     = (int*)carve((size_t)1024*4);
  int* srcs     = (int*)carve((size_t)(E+N)*4);

  // CSR build (6 dispatches)
  hipMemsetAsync(counts, 0, (size_t)N*4, stream);
  k_hist<<<2048, 256, 0, stream>>>(ei, E, N, counts);
  int nb = (N + 1023) / 1024;
  k_scan1<<<nb, 1024, 0, stream>>>(counts, rowptr, bsum, N);
  k_scan2<<<1, 1024, 0, stream>>>(bsum, nb);
  k_scan3<<<(N + 255)/256, 256, 0, stream>>>(rowptr, bsum, counts, cursor, N);
  k_scatter<<<2048, 256, 0, stream>>>(ei, E, N, cursor, srcs);

  // all weight transposes in one launch
  k_transpose_all<<<768, 256, 0, stream>>>(W1, W2, W3, wt1, wt2, wt3);

  int T = (N + 63) / 64;
  int G = (T + 1) / 2;               // two tiles per block, pipelined
  int nodeblocks = (N*64 + 255)/256;

  // layer 1 (A = x in f32, converted during staging)
  k_gemm3<true><<<G, 512, 0, stream>>>(x, wt1, asrc1, adst1, bufH, als, ald, N, T, G);
  k_gather4<0><<<nodeblocks, 256, 0, stream>>>(bufH, rowptr, srcs, als, ald, b1, bufB, nullptr, N);
  // layer 2
  k_gemm3<false><<<G, 512, 0, stream>>>(bufB, wt2, asrc2, adst2, bufH, als, ald, N, T, G);
  k_gather4<0><<<nodeblocks, 256, 0, stream>>>(bufH, rowptr, srcs, als, ald, b2, bufA, nullptr, N);
  // layer 3
  k_gemm3<false><<<G, 512, 0, stream>>>(bufA, wt3, asrc3, adst3, bufH, als, ald, N, T, G);
  k_gather4<1><<<nodeblocks, 256, 0, stream>>>(bufH, rowptr, srcs, als, ald, b3, nullptr, out, N);
}